// Round 3
// baseline (278.838 us; speedup 1.0000x reference)
//
#include <hip/hip_runtime.h>

#define DIM 768
#define SEQ 2048
#define NB 4
#define NH 16
#define DH 48
#define DP 64      // padded head dim
#define BHN (NB*NH)
#define MTOK (NB*SEQ)   // 8192

typedef __attribute__((ext_vector_type(8))) short bf16x8;
typedef __attribute__((ext_vector_type(4))) float f32x4;
typedef __attribute__((ext_vector_type(4))) unsigned int u32x4;

__device__ __forceinline__ unsigned short f32_to_bf16(float f) {
    union { float f; unsigned int u; } v; v.f = f;
    unsigned int r = v.u + 0x7fff + ((v.u >> 16) & 1);
    return (unsigned short)(r >> 16);
}

#if __has_builtin(__builtin_amdgcn_exp2f)
#define EXP2F(x) __builtin_amdgcn_exp2f(x)
#else
#define EXP2F(x) exp2f(x)
#endif

// async global->LDS, 16B per lane; LDS dest is wave-uniform base + lane*16
#define GL_LDS16(g, l) __builtin_amdgcn_global_load_lds( \
    (const __attribute__((address_space(1))) void*)(g),  \
    (__attribute__((address_space(3))) void*)(l), 16, 0, 0)

// ---------------- fp32 -> bf16 converts ----------------
__global__ void cvt_f32_bf16(const float* __restrict__ src, unsigned short* __restrict__ dst, int n) {
    int i = (blockIdx.x * blockDim.x + threadIdx.x) * 4;
    if (i + 3 < n) {
        const float4 v = *(const float4*)(src + i);
        ushort4 o;
        o.x = f32_to_bf16(v.x); o.y = f32_to_bf16(v.y);
        o.z = f32_to_bf16(v.z); o.w = f32_to_bf16(v.w);
        *(ushort4*)(dst + i) = o;
    }
}

// 4 equal-size weight matrices in one launch (blockIdx.y selects)
__global__ void cvt4_f32_bf16(const float* __restrict__ a, const float* __restrict__ b,
                              const float* __restrict__ c, const float* __restrict__ d,
                              unsigned short* __restrict__ dst, int n_each) {
    const float* srcs[4] = {a, b, c, d};
    const float* src = srcs[blockIdx.y];
    unsigned short* out = dst + blockIdx.y * n_each;
    int i = (blockIdx.x * blockDim.x + threadIdx.x) * 4;
    if (i + 3 < n_each) {
        const float4 v = *(const float4*)(src + i);
        ushort4 o;
        o.x = f32_to_bf16(v.x); o.y = f32_to_bf16(v.y);
        o.z = f32_to_bf16(v.z); o.w = f32_to_bf16(v.w);
        *(ushort4*)(out + i) = o;
    }
}

// ---------------- GEMM: Y = X @ W^T + b  (r6 known-good structure) ----------------
// 128x128 tile, BK=32, LDS pitch 32 (no pad), staging via global_load_lds x16B.
// A-tile = 128x32 shorts = 8192 B = 8 chunks of 1024 B; 4 waves x 2 chunks each.
#define BK 32

__global__ __launch_bounds__(256) void qkv_gemm(
    const unsigned short* __restrict__ xb,
    const unsigned short* __restrict__ wb,
    const float* __restrict__ bq, const float* __restrict__ bk, const float* __restrict__ bv,
    unsigned short* __restrict__ Qb, unsigned short* __restrict__ Kb, unsigned short* __restrict__ Vt)
{
    const int z = blockIdx.z;
    const unsigned short* W = wb + z * (DIM * DIM);
    const float* bias = (z == 0) ? bq : (z == 1) ? bk : bv;
    const int row0 = blockIdx.x * 128;
    const int col0 = blockIdx.y * 128;

    __shared__ __align__(16) short As[128 * BK];
    __shared__ __align__(16) short Bs[128 * BK];

    const int tid = threadIdx.x;
    const int lane = tid & 63;
    const int w = tid >> 6;
    const int wy = w >> 1, wx = w & 1;
    const int l15 = lane & 15, quad = lane >> 4;
    const int lr = lane >> 2;          // row within a 16-row chunk
    const int lco = (lane & 3) * 8;    // short offset within row

    f32x4 acc[4][4];
    for (int mi = 0; mi < 4; ++mi) for (int ni = 0; ni < 4; ++ni)
        for (int r = 0; r < 4; ++r) acc[mi][ni][r] = 0.f;

    for (int kt = 0; kt < DIM / BK; ++kt) {
        #pragma unroll
        for (int j = 0; j < 2; ++j) {
            const int c = w * 2 + j;                    // chunk 0..7 (16 rows each)
            GL_LDS16(&xb[(row0 + c * 16 + lr) * DIM + kt * BK + lco], &As[c * 512]);
            GL_LDS16(&W [(col0 + c * 16 + lr) * DIM + kt * BK + lco], &Bs[c * 512]);
        }
        __syncthreads();   // drains vmcnt(0) -> staging visible
        bf16x8 af[4], bfr[4];
        #pragma unroll
        for (int mi = 0; mi < 4; ++mi)
            af[mi] = *(const bf16x8*)&As[(wy * 64 + mi * 16 + l15) * BK + quad * 8];
        #pragma unroll
        for (int ni = 0; ni < 4; ++ni)
            bfr[ni] = *(const bf16x8*)&Bs[(wx * 64 + ni * 16 + l15) * BK + quad * 8];
        #pragma unroll
        for (int mi = 0; mi < 4; ++mi)
            #pragma unroll
            for (int ni = 0; ni < 4; ++ni)
                acc[mi][ni] = __builtin_amdgcn_mfma_f32_16x16x32_bf16(af[mi], bfr[ni], acc[mi][ni], 0, 0, 0);
        __syncthreads();   // all reads done before next overwrite
    }

    // qscale folds 1/sqrt(48) and log2(e) (softmax uses exp2)
    const float qscale = 0.14433756729740643f * 1.4426950408889634f;

    if (z == 2) {
        // V^T epilogue: r-loop is contiguous in s -> pack 4 bf16 = one 8B store
        #pragma unroll
        for (int mi = 0; mi < 4; ++mi) {
            #pragma unroll
            for (int ni = 0; ni < 4; ++ni) {
                int col = col0 + wx * 64 + ni * 16 + l15;
                int h = col / DH, d = col - h * DH;
                int row = row0 + wy * 64 + mi * 16 + quad * 4;   // r=0 token
                int b = row >> 11, s = row & 2047;
                float bi = bias[col];
                union { ushort4 v; unsigned short e[4]; } pk;
                #pragma unroll
                for (int r = 0; r < 4; ++r)
                    pk.e[r] = f32_to_bf16(acc[mi][ni][r] + bi);
                *(ushort4*)&Vt[((b * NH + h) * DP + d) * SEQ + s] = pk.v;
            }
        }
    } else {
        #pragma unroll
        for (int mi = 0; mi < 4; ++mi) {
            #pragma unroll
            for (int ni = 0; ni < 4; ++ni) {
                #pragma unroll
                for (int r = 0; r < 4; ++r) {
                    int row = row0 + wy * 64 + mi * 16 + quad * 4 + r;
                    int col = col0 + wx * 64 + ni * 16 + l15;
                    float v = acc[mi][ni][r] + bias[col];
                    int b = row >> 11, s = row & 2047;
                    int h = col / DH, d = col - h * DH;
                    int bh = b * NH + h;
                    if (z == 0) Qb[(bh * SEQ + s) * DP + d] = f32_to_bf16(v * qscale);
                    else        Kb[(bh * SEQ + s) * DP + d] = f32_to_bf16(v);
                }
            }
        }
    }
}

__global__ __launch_bounds__(256) void out_gemm(
    const unsigned short* __restrict__ ab,
    const unsigned short* __restrict__ Wo,
    const float* __restrict__ bo,
    float* __restrict__ out)
{
    const int row0 = blockIdx.x * 128;
    const int col0 = blockIdx.y * 128;

    __shared__ __align__(16) short As[128 * BK];
    __shared__ __align__(16) short Bs[128 * BK];

    const int tid = threadIdx.x;
    const int lane = tid & 63;
    const int w = tid >> 6;
    const int wy = w >> 1, wx = w & 1;
    const int l15 = lane & 15, quad = lane >> 4;
    const int lr = lane >> 2;
    const int lco = (lane & 3) * 8;

    f32x4 acc[4][4];
    for (int mi = 0; mi < 4; ++mi) for (int ni = 0; ni < 4; ++ni)
        for (int r = 0; r < 4; ++r) acc[mi][ni][r] = 0.f;

    for (int kt = 0; kt < DIM / BK; ++kt) {
        #pragma unroll
        for (int j = 0; j < 2; ++j) {
            const int c = w * 2 + j;                    // chunk 0..7
            GL_LDS16(&ab[(row0 + c * 16 + lr) * DIM + kt * BK + lco], &As[c * 512]);
            GL_LDS16(&Wo[(col0 + c * 16 + lr) * DIM + kt * BK + lco], &Bs[c * 512]);
        }
        __syncthreads();
        bf16x8 af[4], bfr[4];
        #pragma unroll
        for (int mi = 0; mi < 4; ++mi)
            af[mi] = *(const bf16x8*)&As[(wy * 64 + mi * 16 + l15) * BK + quad * 8];
        #pragma unroll
        for (int ni = 0; ni < 4; ++ni)
            bfr[ni] = *(const bf16x8*)&Bs[(wx * 64 + ni * 16 + l15) * BK + quad * 8];
        #pragma unroll
        for (int mi = 0; mi < 4; ++mi)
            #pragma unroll
            for (int ni = 0; ni < 4; ++ni)
                acc[mi][ni] = __builtin_amdgcn_mfma_f32_16x16x32_bf16(af[mi], bfr[ni], acc[mi][ni], 0, 0, 0);
        __syncthreads();
    }

    #pragma unroll
    for (int mi = 0; mi < 4; ++mi)
        #pragma unroll
        for (int ni = 0; ni < 4; ++ni)
            #pragma unroll
            for (int r = 0; r < 4; ++r) {
                int row = row0 + wy * 64 + mi * 16 + quad * 4 + r;
                int col = col0 + wx * 64 + ni * 16 + l15;
                out[row * DIM + col] = acc[mi][ni][r] + bo[col];
            }
}

// ---------------- flash attention: split-K, 64 q-rows/wave ----------------
// 256 threads = 4 waves = 2 q-groups x 2 key-halves. Each wave keeps r0's 64q
// amortization (14 fragment reads serve 4 m-sets, VGPR~120) but only 16 K-tiles.
// Grid (BHN, SEQ/128) = 1024 blocks = 4 blocks/CU -> 4 waves/SIMD (vs r0's 2).
// Two single-buffered 14KB LDS tiles (one per key-half), staged via global_load_lds
// with the XOR swizzle folded into the per-lane GLOBAL source address; K/V LDS
// bases are wave-uniform + loop-invariant (r2's runtime `cur` indexing cost VALU).
// Softmax is an exact sum (no running max) -> split-K combines exactly via one
// in-LDS partial exchange at the end (reusing the K/V LDS, conflict-free layout).
__device__ __forceinline__ int keyperm(int a) {
    return (a & 32) + ((a & 12) << 1) + ((a & 16) >> 2) + (a & 3);
}

__global__ __launch_bounds__(256) void attn_kernel(
    const unsigned short* __restrict__ Qb,
    const unsigned short* __restrict__ Kb,
    const unsigned short* __restrict__ Vt,
    unsigned short* __restrict__ Ob)
{
    const int bh = blockIdx.x;
    const int tile = blockIdx.y;
    const int tid = threadIdx.x;
    const int w = tid >> 6;            // 0..3
    const int qg = w & 1;              // q-group
    const int kh = w >> 1;             // key-half
    const int lane = tid & 63;
    const int l15 = lane & 15, quad = lane >> 4;

    const unsigned short* Qh = Qb + bh * SEQ * DP;
    const unsigned short* Kh = Kb + bh * SEQ * DP;
    const unsigned short* Vh = Vt + bh * DP * SEQ;
    const int q0 = tile * 128 + qg * 64;

    // one 28672B block: Ks[2][64*64] then Vs[2][48*64]; combine scratch aliases all of it
    __shared__ __align__(16) short SMEM[2 * 64 * 64 + 2 * 48 * 64];
    short* KsH = SMEM + kh * (64 * 64);                 // this wave's K tile
    short* VsH = SMEM + 2 * 64 * 64 + kh * (48 * 64);   // this wave's V tile

    // Q B-operand fragments (loop-invariant); zero the d>=48 pad in registers.
    bf16x8 aq[4][2];
    #pragma unroll
    for (int m = 0; m < 4; ++m)
        #pragma unroll
        for (int ks = 0; ks < 2; ++ks)
            aq[m][ks] = *(const bf16x8*)&Qh[(q0 + m * 16 + l15) * DP + ks * 32 + quad * 8];
    if (quad >= 2) {
        const bf16x8 z8 = {0, 0, 0, 0, 0, 0, 0, 0};
        #pragma unroll
        for (int m = 0; m < 4; ++m) aq[m][1] = z8;
    }

    f32x4 o[4][3];
    #pragma unroll
    for (int m = 0; m < 4; ++m) for (int ni = 0; ni < 3; ++ni)
        for (int r = 0; r < 4; ++r) o[m][ni][r] = 0.f;
    float ls[4][2];
    #pragma unroll
    for (int m = 0; m < 4; ++m) { ls[m][0] = 0.f; ls[m][1] = 0.f; }

    const f32x4 FZ = {0.f, 0.f, 0.f, 0.f};   // loop-invariant zero C operand

    // ---- staging geometry: 1024B chunks, lane writes chunk_base + lane*16 ----
    // row ra = c*8 + (lane>>3), chunk-in-row pcc = lane&7, swizzle folded into source.
    // Per key-half tile: K = 8 chunks, V = 6 chunks; split between the 2 waves of
    // this half by qg: wave stages K chunks qg*4+j (j<4), V chunks qg*3+j (j<3).
    const int lr3 = lane >> 3, pcc = lane & 7;
    const int swz8 = (pcc ^ lr3) * 8;            // swizzled short offset within row
    int kso[4], vso[3];
    #pragma unroll
    for (int j = 0; j < 4; ++j) {
        const int ra = (qg * 4 + j) * 8 + lr3;
        kso[j] = keyperm(ra) * DP + swz8;        // + k0*DP at issue time
    }
    #pragma unroll
    for (int j = 0; j < 3; ++j) {
        const int ra = (qg * 3 + j) * 8 + lr3;
        vso[j] = ra * SEQ + swz8;                // + k0 at issue time
    }

    for (int kt = 0; kt < SEQ / 128; ++kt) {
        const int k0 = (kh * (SEQ / 128) + kt) * 64;   // this half's key tile
        __syncthreads();   // all waves done reading the previous tiles
        #pragma unroll
        for (int j = 0; j < 4; ++j)
            GL_LDS16(&Kh[k0 * DP + kso[j]], &KsH[(qg * 4 + j) * 512]);
        #pragma unroll
        for (int j = 0; j < 3; ++j)
            GL_LDS16(&Vh[k0 + vso[j]], &VsH[(qg * 3 + j) * 512]);
        __syncthreads();   // per-wave vmcnt(0) drain before barrier -> tiles staged

        // ---- K/V fragments: read once, serve all 4 m-sets ----
        bf16x8 ak0[4], ak1[4];
        #pragma unroll
        for (int n = 0; n < 4; ++n) {
            ak0[n] = *(const bf16x8*)&KsH[(n * 16 + l15) * 64 + ((quad ^ (l15 & 7)) * 8)];
            ak1[n] = *(const bf16x8*)&KsH[(n * 16 + l15) * 64 + (((4 + quad) ^ (l15 & 7)) * 8)];
        }
        bf16x8 av[2][3];
        #pragma unroll
        for (int ks = 0; ks < 2; ++ks)
            #pragma unroll
            for (int mt = 0; mt < 3; ++mt)
                av[ks][mt] = *(const bf16x8*)&VsH[(mt * 16 + l15) * 64 + (((ks * 4 + quad) ^ (l15 & 7)) * 8)];

        // ---- process 4 m-sets in two pairs (register pressure) ----
        #pragma unroll
        for (int mp = 0; mp < 2; ++mp) {
            const int m0 = 2 * mp, m1 = 2 * mp + 1;
            // S^T = K · Q^T
            f32x4 sc[2][4];
            __builtin_amdgcn_s_setprio(1);
            #pragma unroll
            for (int n = 0; n < 4; ++n) {
                sc[0][n] = __builtin_amdgcn_mfma_f32_16x16x32_bf16(ak0[n], aq[m0][0], FZ, 0, 0, 0);
                sc[1][n] = __builtin_amdgcn_mfma_f32_16x16x32_bf16(ak0[n], aq[m1][0], FZ, 0, 0, 0);
            }
            #pragma unroll
            for (int n = 0; n < 4; ++n) {
                sc[0][n] = __builtin_amdgcn_mfma_f32_16x16x32_bf16(ak1[n], aq[m0][1], sc[0][n], 0, 0, 0);
                sc[1][n] = __builtin_amdgcn_mfma_f32_16x16x32_bf16(ak1[n], aq[m1][1], sc[1][n], 0, 0, 0);
            }
            __builtin_amdgcn_s_setprio(0);
            // P = exp2(S^T); pack 2 vals/instr; 2 lsum chains per m
            union { u32x4 u; bf16x8 h; } bp[2][2];   // [mi][ks]
            #pragma unroll
            for (int mi = 0; mi < 2; ++mi) {
                #pragma unroll
                for (int ks = 0; ks < 2; ++ks) {
                    #pragma unroll
                    for (int w2 = 0; w2 < 4; ++w2) {
                        const int j0 = 2 * w2, j1 = 2 * w2 + 1;
                        float p0 = EXP2F(sc[mi][2 * ks + (j0 >> 2)][j0 & 3]);
                        float p1 = EXP2F(sc[mi][2 * ks + (j1 >> 2)][j1 & 3]);
                        ls[2 * mp + mi][w2 & 1] += (p0 + p1);
                        bp[mi][ks].u[w2] = __builtin_amdgcn_perm(__float_as_uint(p1), __float_as_uint(p0), 0x07060302u);
                    }
                }
            }
            // O += P V
            __builtin_amdgcn_s_setprio(1);
            #pragma unroll
            for (int ks = 0; ks < 2; ++ks)
                #pragma unroll
                for (int mt = 0; mt < 3; ++mt) {
                    o[m0][mt] = __builtin_amdgcn_mfma_f32_16x16x32_bf16(av[ks][mt], bp[0][ks].h, o[m0][mt], 0, 0, 0);
                    o[m1][mt] = __builtin_amdgcn_mfma_f32_16x16x32_bf16(av[ks][mt], bp[1][ks].h, o[m1][mt], 0, 0, 0);
                }
            __builtin_amdgcn_s_setprio(0);
        }
    }

    // ---- split-K combine: kh=1 waves park partials in LDS, kh=0 waves finish ----
    // Exact: softmax here is sum-of-exp2 (no running max), so partial O and partial
    // lsum chains just add. Layout: region qg*3584 floats; addr = idx*64 + lane
    // (consecutive lanes -> consecutive banks; 2-way alias is free).
    __syncthreads();                      // K/V LDS dead, safe to reuse
    float* sh = (float*)SMEM;
    if (kh == 1) {
        float* dst = sh + qg * 3584 + lane;
        #pragma unroll
        for (int m = 0; m < 4; ++m) {
            #pragma unroll
            for (int mt = 0; mt < 3; ++mt)
                #pragma unroll
                for (int r = 0; r < 4; ++r)
                    dst[((m * 3 + mt) * 4 + r) * 64] = o[m][mt][r];
            dst[(48 + 2 * m) * 64] = ls[m][0];
            dst[(49 + 2 * m) * 64] = ls[m][1];
        }
    }
    __syncthreads();
    if (kh == 0) {
        const float* src = sh + qg * 3584 + lane;
        const int b = bh >> 4, h = bh & 15;
        #pragma unroll
        for (int m = 0; m < 4; ++m) {
            #pragma unroll
            for (int mt = 0; mt < 3; ++mt)
                #pragma unroll
                for (int r = 0; r < 4; ++r)
                    o[m][mt][r] += src[((m * 3 + mt) * 4 + r) * 64];
            float lsum = (ls[m][0] + src[(48 + 2 * m) * 64])
                       + (ls[m][1] + src[(49 + 2 * m) * 64]);
            lsum += __shfl_xor(lsum, 16);
            lsum += __shfl_xor(lsum, 32);
            float inv = 1.f / lsum;
            int token = b * SEQ + q0 + m * 16 + l15;
            #pragma unroll
            for (int mt = 0; mt < 3; ++mt) {
                union { ushort4 v; unsigned short e[4]; } pk;
                #pragma unroll
                for (int r = 0; r < 4; ++r)
                    pk.e[r] = f32_to_bf16(o[m][mt][r] * inv);
                *(ushort4*)&Ob[token * DIM + h * DH + mt * 16 + quad * 4] = pk.v;
            }
        }
    }
}

// ---------------- launch ----------------
extern "C" void kernel_launch(void* const* d_in, const int* in_sizes, int n_in,
                              void* d_out, int out_size, void* d_ws, size_t ws_size,
                              hipStream_t stream) {
    const float* x  = (const float*)d_in[0];
    const float* Wq = (const float*)d_in[1]; const float* bq = (const float*)d_in[2];
    const float* Wk = (const float*)d_in[3]; const float* bk = (const float*)d_in[4];
    const float* Wv = (const float*)d_in[5]; const float* bv = (const float*)d_in[6];
    const float* Wo = (const float*)d_in[7]; const float* bo = (const float*)d_in[8];

    unsigned char* ws = (unsigned char*)d_ws;
    unsigned short* xb = (unsigned short*)(ws);                         // 12,582,912 B
    unsigned short* wb = (unsigned short*)(ws + 12582912);              //  4,718,592 B
    unsigned short* Qb = (unsigned short*)(ws + 17301504);              // 16,777,216 B
    unsigned short* Kb = (unsigned short*)(ws + 34078720);              // 16,777,216 B
    unsigned short* Vt = (unsigned short*)(ws + 50855936);              // 16,777,216 B
    unsigned short* Ob = (unsigned short*)(ws + 67633152);              // 12,582,912 B

    cvt_f32_bf16<<<6144, 256, 0, stream>>>(x, xb, MTOK * DIM);
    cvt4_f32_bf16<<<dim3(576, 4), 256, 0, stream>>>(Wq, Wk, Wv, Wo, wb, DIM * DIM);

    qkv_gemm<<<dim3(MTOK / 128, DIM / 128, 3), 256, 0, stream>>>(xb, wb, bq, bk, bv, Qb, Kb, Vt);
    attn_kernel<<<dim3(BHN, SEQ / 128), 256, 0, stream>>>(Qb, Kb, Vt, Ob);
    out_gemm<<<dim3(MTOK / 128, DIM / 128), 256, 0, stream>>>(Ob, wb + 3 * DIM * DIM, bo, (float*)d_out);
}

// Round 4
// 271.396 us; speedup vs baseline: 1.0274x; 1.0274x over previous
//
#include <hip/hip_runtime.h>

#define DIM 768
#define SEQ 2048
#define NB 4
#define NH 16
#define DH 48
#define DP 64      // padded head dim
#define BHN (NB*NH)
#define MTOK (NB*SEQ)   // 8192

typedef __attribute__((ext_vector_type(8))) short bf16x8;
typedef __attribute__((ext_vector_type(4))) float f32x4;
typedef __attribute__((ext_vector_type(4))) unsigned int u32x4;

__device__ __forceinline__ unsigned short f32_to_bf16(float f) {
    union { float f; unsigned int u; } v; v.f = f;
    unsigned int r = v.u + 0x7fff + ((v.u >> 16) & 1);
    return (unsigned short)(r >> 16);
}

#if __has_builtin(__builtin_amdgcn_exp2f)
#define EXP2F(x) __builtin_amdgcn_exp2f(x)
#else
#define EXP2F(x) exp2f(x)
#endif

// async global->LDS, 16B per lane; LDS dest is wave-uniform base + lane*16
#define GL_LDS16(g, l) __builtin_amdgcn_global_load_lds( \
    (const __attribute__((address_space(1))) void*)(g),  \
    (__attribute__((address_space(3))) void*)(l), 16, 0, 0)

// ---------------- fp32 -> bf16 converts ----------------
__global__ void cvt_f32_bf16(const float* __restrict__ src, unsigned short* __restrict__ dst, int n) {
    int i = (blockIdx.x * blockDim.x + threadIdx.x) * 4;
    if (i + 3 < n) {
        const float4 v = *(const float4*)(src + i);
        ushort4 o;
        o.x = f32_to_bf16(v.x); o.y = f32_to_bf16(v.y);
        o.z = f32_to_bf16(v.z); o.w = f32_to_bf16(v.w);
        *(ushort4*)(dst + i) = o;
    }
}

// 4 equal-size weight matrices in one launch (blockIdx.y selects)
__global__ void cvt4_f32_bf16(const float* __restrict__ a, const float* __restrict__ b,
                              const float* __restrict__ c, const float* __restrict__ d,
                              unsigned short* __restrict__ dst, int n_each) {
    const float* srcs[4] = {a, b, c, d};
    const float* src = srcs[blockIdx.y];
    unsigned short* out = dst + blockIdx.y * n_each;
    int i = (blockIdx.x * blockDim.x + threadIdx.x) * 4;
    if (i + 3 < n_each) {
        const float4 v = *(const float4*)(src + i);
        ushort4 o;
        o.x = f32_to_bf16(v.x); o.y = f32_to_bf16(v.y);
        o.z = f32_to_bf16(v.z); o.w = f32_to_bf16(v.w);
        *(ushort4*)(out + i) = o;
    }
}

// Vt pad rows: row 48 = bf16(1.0) (MFMA-computed softmax denominator),
// rows 49..63 = 0 (clean zeros in the mt=3 PV accumulator).
__global__ void vt_pad_init(unsigned short* __restrict__ Vt) {
    const int bhd = blockIdx.x;                  // bh
    const int d = 48 + blockIdx.y;               // 48..63
    const unsigned short val = (blockIdx.y == 0) ? (unsigned short)0x3F80 : (unsigned short)0;
    ushort4 v4 = {val, val, val, val};
    ushort4* dst = (ushort4*)&Vt[(bhd * DP + d) * SEQ];
    for (int i = threadIdx.x; i < SEQ / 4; i += 256) dst[i] = v4;
}

// ---------------- GEMM: Y = X @ W^T + b ----------------
// 128x128 tile, BK=32, LDS pitch 32, staging via global_load_lds x16B.
// Double-buffered, stage-early, ONE barrier per kt: next tile's loads are in
// flight across the ds_read+MFMA of the current tile (latency partially hidden
// instead of fully exposed at an immediate drain barrier). kt unrolled x2 for
// static LDS buffer indices.
#define BK 32

__global__ __launch_bounds__(256) void qkv_gemm(
    const unsigned short* __restrict__ xb,
    const unsigned short* __restrict__ wb,
    const float* __restrict__ bq, const float* __restrict__ bk, const float* __restrict__ bv,
    unsigned short* __restrict__ Qb, unsigned short* __restrict__ Kb, unsigned short* __restrict__ Vt)
{
    const int z = blockIdx.z;
    const unsigned short* W = wb + z * (DIM * DIM);
    const float* bias = (z == 0) ? bq : (z == 1) ? bk : bv;
    const int row0 = blockIdx.x * 128;
    const int col0 = blockIdx.y * 128;

    __shared__ __align__(16) short As[2][128 * BK];
    __shared__ __align__(16) short Bs[2][128 * BK];

    const int tid = threadIdx.x;
    const int lane = tid & 63;
    const int w = tid >> 6;
    const int wy = w >> 1, wx = w & 1;
    const int l15 = lane & 15, quad = lane >> 4;
    const int lr = lane >> 2;          // row within a 16-row chunk
    const int lco = (lane & 3) * 8;    // short offset within row

    f32x4 acc[4][4];
    for (int mi = 0; mi < 4; ++mi) for (int ni = 0; ni < 4; ++ni)
        for (int r = 0; r < 4; ++r) acc[mi][ni][r] = 0.f;

#define QKV_STAGE(B, KT) do { \
    _Pragma("unroll") \
    for (int j = 0; j < 2; ++j) { \
        const int c = w * 2 + j; \
        GL_LDS16(&xb[(row0 + c * 16 + lr) * DIM + (KT) * BK + lco], &As[B][c * 512]); \
        GL_LDS16(&W [(col0 + c * 16 + lr) * DIM + (KT) * BK + lco], &Bs[B][c * 512]); \
    } } while (0)

#define QKV_COMPUTE(B) do { \
    bf16x8 af[4], bfr[4]; \
    _Pragma("unroll") \
    for (int mi = 0; mi < 4; ++mi) \
        af[mi] = *(const bf16x8*)&As[B][(wy * 64 + mi * 16 + l15) * BK + quad * 8]; \
    _Pragma("unroll") \
    for (int ni = 0; ni < 4; ++ni) \
        bfr[ni] = *(const bf16x8*)&Bs[B][(wx * 64 + ni * 16 + l15) * BK + quad * 8]; \
    _Pragma("unroll") \
    for (int mi = 0; mi < 4; ++mi) \
        _Pragma("unroll") \
        for (int ni = 0; ni < 4; ++ni) \
            acc[mi][ni] = __builtin_amdgcn_mfma_f32_16x16x32_bf16(af[mi], bfr[ni], acc[mi][ni], 0, 0, 0); \
    } while (0)

    QKV_STAGE(0, 0);
    __syncthreads();
    for (int kt = 0; kt < DIM / BK; kt += 2) {
        QKV_STAGE(1, kt + 1);
        QKV_COMPUTE(0);
        __syncthreads();
        if (kt + 2 < DIM / BK) QKV_STAGE(0, kt + 2);
        QKV_COMPUTE(1);
        __syncthreads();
    }

    // qscale folds 1/sqrt(48) and log2(e) (softmax uses exp2)
    const float qscale = 0.14433756729740643f * 1.4426950408889634f;

    if (z == 2) {
        // V^T epilogue: r-loop is contiguous in s -> pack 4 bf16 = one 8B store
        #pragma unroll
        for (int mi = 0; mi < 4; ++mi) {
            #pragma unroll
            for (int ni = 0; ni < 4; ++ni) {
                int col = col0 + wx * 64 + ni * 16 + l15;
                int h = col / DH, d = col - h * DH;
                int row = row0 + wy * 64 + mi * 16 + quad * 4;   // r=0 token
                int b = row >> 11, s = row & 2047;
                float bi = bias[col];
                union { ushort4 v; unsigned short e[4]; } pk;
                #pragma unroll
                for (int r = 0; r < 4; ++r)
                    pk.e[r] = f32_to_bf16(acc[mi][ni][r] + bi);
                *(ushort4*)&Vt[((b * NH + h) * DP + d) * SEQ + s] = pk.v;
            }
        }
    } else {
        #pragma unroll
        for (int mi = 0; mi < 4; ++mi) {
            #pragma unroll
            for (int ni = 0; ni < 4; ++ni) {
                #pragma unroll
                for (int r = 0; r < 4; ++r) {
                    int row = row0 + wy * 64 + mi * 16 + quad * 4 + r;
                    int col = col0 + wx * 64 + ni * 16 + l15;
                    float v = acc[mi][ni][r] + bias[col];
                    int b = row >> 11, s = row & 2047;
                    int h = col / DH, d = col - h * DH;
                    int bh = b * NH + h;
                    if (z == 0) Qb[(bh * SEQ + s) * DP + d] = f32_to_bf16(v * qscale);
                    else        Kb[(bh * SEQ + s) * DP + d] = f32_to_bf16(v);
                }
            }
        }
    }
}

__global__ __launch_bounds__(256) void out_gemm(
    const unsigned short* __restrict__ ab,
    const unsigned short* __restrict__ Wo,
    const float* __restrict__ bo,
    float* __restrict__ out)
{
    const int row0 = blockIdx.x * 128;
    const int col0 = blockIdx.y * 128;

    __shared__ __align__(16) short As[2][128 * BK];
    __shared__ __align__(16) short Bs[2][128 * BK];

    const int tid = threadIdx.x;
    const int lane = tid & 63;
    const int w = tid >> 6;
    const int wy = w >> 1, wx = w & 1;
    const int l15 = lane & 15, quad = lane >> 4;
    const int lr = lane >> 2;
    const int lco = (lane & 3) * 8;

    f32x4 acc[4][4];
    for (int mi = 0; mi < 4; ++mi) for (int ni = 0; ni < 4; ++ni)
        for (int r = 0; r < 4; ++r) acc[mi][ni][r] = 0.f;

#define OUT_STAGE(B, KT) do { \
    _Pragma("unroll") \
    for (int j = 0; j < 2; ++j) { \
        const int c = w * 2 + j; \
        GL_LDS16(&ab[(row0 + c * 16 + lr) * DIM + (KT) * BK + lco], &As[B][c * 512]); \
        GL_LDS16(&Wo[(col0 + c * 16 + lr) * DIM + (KT) * BK + lco], &Bs[B][c * 512]); \
    } } while (0)

    OUT_STAGE(0, 0);
    __syncthreads();
    for (int kt = 0; kt < DIM / BK; kt += 2) {
        OUT_STAGE(1, kt + 1);
        QKV_COMPUTE(0);
        __syncthreads();
        if (kt + 2 < DIM / BK) OUT_STAGE(0, kt + 2);
        QKV_COMPUTE(1);
        __syncthreads();
    }

    #pragma unroll
    for (int mi = 0; mi < 4; ++mi)
        #pragma unroll
        for (int ni = 0; ni < 4; ++ni)
            #pragma unroll
            for (int r = 0; r < 4; ++r) {
                int row = row0 + wy * 64 + mi * 16 + quad * 4 + r;
                int col = col0 + wx * 64 + ni * 16 + l15;
                out[row * DIM + col] = acc[mi][ni][r] + bo[col];
            }
}

// ---------------- flash attention: 64 q-rows/wave (r0 structure) ----------------
// 256 threads = 4 waves, 256 q-rows/block; grid (BHN, SEQ/256) = 512 blocks,
// 2 blocks/CU. Deltas vs r0 (69.8us):
//  (a) staging remap ra=tid>>3, pc=tid&7: wave ds_writes are lane*16 sequential
//      -> bank-conflict-free (r0's ra=tid>>2/pc=tid&3 used half the banks: 1.8M conflicts).
//  (b) V extended to 64 rows; global row 48 = 1.0, 49..63 = 0 (vt_pad_init).
//      PV mt=3 then computes lsum = sum(P) in o[m][3][0] via MFMA -- removes the
//      64 VALU adds/kt/wave lsum chain (~45% of VALU busy).
//  (c) s_setprio(1) around MFMA clusters (T5; de-phases the 2 co-resident blocks).
__device__ __forceinline__ int keyperm(int a) {
    return (a & 32) + ((a & 12) << 1) + ((a & 16) >> 2) + (a & 3);
}

__global__ __launch_bounds__(256) void attn_kernel(
    const unsigned short* __restrict__ Qb,
    const unsigned short* __restrict__ Kb,
    const unsigned short* __restrict__ Vt,
    unsigned short* __restrict__ Ob)
{
    const int bh = blockIdx.x;
    const int tile = blockIdx.y;
    const int tid = threadIdx.x;
    const int w = tid >> 6;            // 0..3
    const int lane = tid & 63;
    const int l15 = lane & 15, quad = lane >> 4;

    const unsigned short* Qh = Qb + bh * SEQ * DP;
    const unsigned short* Kh = Kb + bh * SEQ * DP;
    const unsigned short* Vh = Vt + bh * DP * SEQ;
    const int q0 = tile * 256 + w * 64;

    // pitch 64 shorts (128B), 16B-chunk XOR swizzle (phys chunk = logical ^ (row&7)),
    // absorbed into the global source address at staging time.
    __shared__ __align__(16) short Ks[64 * 64];   // [key slot a -> global key keyperm(a)][d]
    __shared__ __align__(16) short Vs[64 * 64];   // [d][key]; rows 48..63 = pad (48 = ones)

    // Q B-operand fragments (loop-invariant); zero the d>=48 pad in registers.
    bf16x8 aq[4][2];
    #pragma unroll
    for (int m = 0; m < 4; ++m)
        #pragma unroll
        for (int ks = 0; ks < 2; ++ks)
            aq[m][ks] = *(const bf16x8*)&Qh[(q0 + m * 16 + l15) * DP + ks * 32 + quad * 8];
    if (quad >= 2) {
        const bf16x8 z8 = {0, 0, 0, 0, 0, 0, 0, 0};
        #pragma unroll
        for (int m = 0; m < 4; ++m) aq[m][1] = z8;
    }

    f32x4 o[4][4];     // [m][mt]; mt=3 row48 = lsum accumulator
    #pragma unroll
    for (int m = 0; m < 4; ++m) for (int ni = 0; ni < 4; ++ni)
        for (int r = 0; r < 4; ++r) o[m][ni][r] = 0.f;

    const f32x4 FZ = {0.f, 0.f, 0.f, 0.f};   // loop-invariant zero C operand

    // staging: 256 threads; row ra = tid>>3 (0..31) and ra+32; chunk pc = tid&7.
    // Wave lanes write LDS bytes at lane*16 sequential -> conflict-free.
    // Swizzled source chunk = pc ^ (ra&7); identical for ra and ra+32.
    // keyperm(ra+32) = keyperm(ra) + 32 (bit5 passthrough).
    const int ra = tid >> 3;
    const int pc = tid & 7;
    const int lc = (pc ^ (ra & 7)) * 8;          // swizzled short offset within row
    const int kaR = keyperm(ra);
    const int ldsA = ra * 64 + pc * 8;
    const int ldsB = ldsA + 32 * 64;

    bf16x8 kr0, kr1, vr0, vr1;
    kr0 = *(const bf16x8*)&Kh[kaR * DP + lc];
    kr1 = *(const bf16x8*)&Kh[(kaR + 32) * DP + lc];
    vr0 = *(const bf16x8*)&Vh[ra * SEQ + lc];
    vr1 = *(const bf16x8*)&Vh[(ra + 32) * SEQ + lc];

    for (int kt = 0; kt < SEQ / 64; ++kt) {
        __syncthreads();
        *(bf16x8*)&Ks[ldsA] = kr0;
        *(bf16x8*)&Ks[ldsB] = kr1;
        *(bf16x8*)&Vs[ldsA] = vr0;
        *(bf16x8*)&Vs[ldsB] = vr1;
        if (kt + 1 < SEQ / 64) {
            const int k0n = (kt + 1) * 64;
            kr0 = *(const bf16x8*)&Kh[(k0n + kaR) * DP + lc];
            kr1 = *(const bf16x8*)&Kh[(k0n + kaR + 32) * DP + lc];
            vr0 = *(const bf16x8*)&Vh[ra * SEQ + k0n + lc];
            vr1 = *(const bf16x8*)&Vh[(ra + 32) * SEQ + k0n + lc];
        }
        __syncthreads();

        // ---- K/V fragments: read once, serve all 4 m-sets ----
        bf16x8 ak0[4], ak1[4];
        #pragma unroll
        for (int n = 0; n < 4; ++n) {
            ak0[n] = *(const bf16x8*)&Ks[(n * 16 + l15) * 64 + ((quad ^ (l15 & 7)) * 8)];
            ak1[n] = *(const bf16x8*)&Ks[(n * 16 + l15) * 64 + (((4 + quad) ^ (l15 & 7)) * 8)];
        }
        bf16x8 av[2][4];
        #pragma unroll
        for (int ks = 0; ks < 2; ++ks)
            #pragma unroll
            for (int mt = 0; mt < 4; ++mt)
                av[ks][mt] = *(const bf16x8*)&Vs[(mt * 16 + l15) * 64 + (((ks * 4 + quad) ^ (l15 & 7)) * 8)];

        // ---- process 4 m-sets in two pairs (register pressure) ----
        #pragma unroll
        for (int mp = 0; mp < 2; ++mp) {
            const int m0 = 2 * mp, m1 = 2 * mp + 1;
            // S^T = K · Q^T
            f32x4 sc[2][4];
            __builtin_amdgcn_s_setprio(1);
            #pragma unroll
            for (int n = 0; n < 4; ++n) {
                sc[0][n] = __builtin_amdgcn_mfma_f32_16x16x32_bf16(ak0[n], aq[m0][0], FZ, 0, 0, 0);
                sc[1][n] = __builtin_amdgcn_mfma_f32_16x16x32_bf16(ak0[n], aq[m1][0], FZ, 0, 0, 0);
            }
            #pragma unroll
            for (int n = 0; n < 4; ++n) {
                sc[0][n] = __builtin_amdgcn_mfma_f32_16x16x32_bf16(ak1[n], aq[m0][1], sc[0][n], 0, 0, 0);
                sc[1][n] = __builtin_amdgcn_mfma_f32_16x16x32_bf16(ak1[n], aq[m1][1], sc[1][n], 0, 0, 0);
            }
            __builtin_amdgcn_s_setprio(0);
            // P = exp2(S^T); pack 2 vals/instr (no scalar lsum chain -- MFMA row 48 does it)
            union { u32x4 u; bf16x8 h; } bp[2][2];   // [mi][ks]
            #pragma unroll
            for (int mi = 0; mi < 2; ++mi) {
                #pragma unroll
                for (int ks = 0; ks < 2; ++ks) {
                    #pragma unroll
                    for (int w2 = 0; w2 < 4; ++w2) {
                        const int j0 = 2 * w2, j1 = 2 * w2 + 1;
                        float p0 = EXP2F(sc[mi][2 * ks + (j0 >> 2)][j0 & 3]);
                        float p1 = EXP2F(sc[mi][2 * ks + (j1 >> 2)][j1 & 3]);
                        bp[mi][ks].u[w2] = __builtin_amdgcn_perm(__float_as_uint(p1), __float_as_uint(p0), 0x07060302u);
                    }
                }
            }
            // O += P V   (mt=3: V row 48 = ones -> o[m][3][0]@quad0 = lsum)
            __builtin_amdgcn_s_setprio(1);
            #pragma unroll
            for (int ks = 0; ks < 2; ++ks)
                #pragma unroll
                for (int mt = 0; mt < 4; ++mt) {
                    o[m0][mt] = __builtin_amdgcn_mfma_f32_16x16x32_bf16(av[ks][mt], bp[0][ks].h, o[m0][mt], 0, 0, 0);
                    o[m1][mt] = __builtin_amdgcn_mfma_f32_16x16x32_bf16(av[ks][mt], bp[1][ks].h, o[m1][mt], 0, 0, 0);
                }
            __builtin_amdgcn_s_setprio(0);
        }
    }

    // ---- lsum lives in o[m][3][0] at quad 0 (d=48 row): broadcast, scale, store ----
    const int b = bh >> 4, h = bh & 15;
    #pragma unroll
    for (int m = 0; m < 4; ++m) {
        float lsum = __shfl(o[m][3][0], l15);   // src lane l15 (quad 0) holds q-row l15's sum
        float inv = 1.f / lsum;
        int token = b * SEQ + q0 + m * 16 + l15;
        #pragma unroll
        for (int mt = 0; mt < 3; ++mt) {
            union { ushort4 v; unsigned short e[4]; } pk;
            #pragma unroll
            for (int r = 0; r < 4; ++r)
                pk.e[r] = f32_to_bf16(o[m][mt][r] * inv);
            *(ushort4*)&Ob[token * DIM + h * DH + mt * 16 + quad * 4] = pk.v;
        }
    }
}

// ---------------- launch ----------------
extern "C" void kernel_launch(void* const* d_in, const int* in_sizes, int n_in,
                              void* d_out, int out_size, void* d_ws, size_t ws_size,
                              hipStream_t stream) {
    const float* x  = (const float*)d_in[0];
    const float* Wq = (const float*)d_in[1]; const float* bq = (const float*)d_in[2];
    const float* Wk = (const float*)d_in[3]; const float* bk = (const float*)d_in[4];
    const float* Wv = (const float*)d_in[5]; const float* bv = (const float*)d_in[6];
    const float* Wo = (const float*)d_in[7]; const float* bo = (const float*)d_in[8];

    unsigned char* ws = (unsigned char*)d_ws;
    unsigned short* xb = (unsigned short*)(ws);                         // 12,582,912 B
    unsigned short* wb = (unsigned short*)(ws + 12582912);              //  4,718,592 B
    unsigned short* Qb = (unsigned short*)(ws + 17301504);              // 16,777,216 B
    unsigned short* Kb = (unsigned short*)(ws + 34078720);              // 16,777,216 B
    unsigned short* Vt = (unsigned short*)(ws + 50855936);              // 16,777,216 B
    unsigned short* Ob = (unsigned short*)(ws + 67633152);              // 12,582,912 B

    cvt_f32_bf16<<<6144, 256, 0, stream>>>(x, xb, MTOK * DIM);
    cvt4_f32_bf16<<<dim3(576, 4), 256, 0, stream>>>(Wq, Wk, Wv, Wo, wb, DIM * DIM);
    vt_pad_init<<<dim3(BHN, 16), 256, 0, stream>>>(Vt);

    qkv_gemm<<<dim3(MTOK / 128, DIM / 128, 3), 256, 0, stream>>>(xb, wb, bq, bk, bv, Qb, Kb, Vt);
    attn_kernel<<<dim3(BHN, SEQ / 256), 256, 0, stream>>>(Qb, Kb, Vt, Ob);
    out_gemm<<<dim3(MTOK / 128, DIM / 128), 256, 0, stream>>>(Ob, wb + 3 * DIM * DIM, bo, (float*)d_out);
}

// Round 5
// 247.853 us; speedup vs baseline: 1.1250x; 1.0950x over previous
//
#include <hip/hip_runtime.h>

#define DIM 768
#define SEQ 2048
#define NB 4
#define NH 16
#define DH 48
#define DP 64      // padded head dim
#define BHN (NB*NH)
#define MTOK (NB*SEQ)   // 8192

typedef __attribute__((ext_vector_type(8))) short bf16x8;
typedef __attribute__((ext_vector_type(4))) float f32x4;
typedef __attribute__((ext_vector_type(4))) unsigned int u32x4;

__device__ __forceinline__ unsigned short f32_to_bf16(float f) {
    union { float f; unsigned int u; } v; v.f = f;
    unsigned int r = v.u + 0x7fff + ((v.u >> 16) & 1);
    return (unsigned short)(r >> 16);
}

#if __has_builtin(__builtin_amdgcn_exp2f)
#define EXP2F(x) __builtin_amdgcn_exp2f(x)
#else
#define EXP2F(x) exp2f(x)
#endif

// async global->LDS, 16B per lane; LDS dest is wave-uniform base + lane*16
#define GL_LDS16(g, l) __builtin_amdgcn_global_load_lds( \
    (const __attribute__((address_space(1))) void*)(g),  \
    (__attribute__((address_space(3))) void*)(l), 16, 0, 0)

// ---------------- fp32 -> bf16 converts ----------------
__global__ void cvt_f32_bf16(const float* __restrict__ src, unsigned short* __restrict__ dst, int n) {
    int i = (blockIdx.x * blockDim.x + threadIdx.x) * 4;
    if (i + 3 < n) {
        const float4 v = *(const float4*)(src + i);
        ushort4 o;
        o.x = f32_to_bf16(v.x); o.y = f32_to_bf16(v.y);
        o.z = f32_to_bf16(v.z); o.w = f32_to_bf16(v.w);
        *(ushort4*)(dst + i) = o;
    }
}

// 4 equal-size weight matrices in one launch (blockIdx.y selects)
__global__ void cvt4_f32_bf16(const float* __restrict__ a, const float* __restrict__ b,
                              const float* __restrict__ c, const float* __restrict__ d,
                              unsigned short* __restrict__ dst, int n_each) {
    const float* srcs[4] = {a, b, c, d};
    const float* src = srcs[blockIdx.y];
    unsigned short* out = dst + blockIdx.y * n_each;
    int i = (blockIdx.x * blockDim.x + threadIdx.x) * 4;
    if (i + 3 < n_each) {
        const float4 v = *(const float4*)(src + i);
        ushort4 o;
        o.x = f32_to_bf16(v.x); o.y = f32_to_bf16(v.y);
        o.z = f32_to_bf16(v.z); o.w = f32_to_bf16(v.w);
        *(ushort4*)(out + i) = o;
    }
}

// ---------------- GEMM: Y = X @ W^T + b  (r0 known-good structure) ----------------
// 128x128 tile, BK=32, LDS pitch 32 (no pad), staging via global_load_lds x16B.
// A-tile = 128x32 shorts = 8192 B = 8 chunks of 1024 B; 4 waves x 2 chunks each.
#define BK 32

__global__ __launch_bounds__(256) void qkv_gemm(
    const unsigned short* __restrict__ xb,
    const unsigned short* __restrict__ wb,
    const float* __restrict__ bq, const float* __restrict__ bk, const float* __restrict__ bv,
    unsigned short* __restrict__ Qb, unsigned short* __restrict__ Kb, unsigned short* __restrict__ Vt)
{
    const int z = blockIdx.z;
    const unsigned short* W = wb + z * (DIM * DIM);
    const float* bias = (z == 0) ? bq : (z == 1) ? bk : bv;
    const int row0 = blockIdx.x * 128;
    const int col0 = blockIdx.y * 128;

    __shared__ __align__(16) short As[128 * BK];
    __shared__ __align__(16) short Bs[128 * BK];

    const int tid = threadIdx.x;
    const int lane = tid & 63;
    const int w = tid >> 6;
    const int wy = w >> 1, wx = w & 1;
    const int l15 = lane & 15, quad = lane >> 4;
    const int lr = lane >> 2;          // row within a 16-row chunk
    const int lco = (lane & 3) * 8;    // short offset within row

    f32x4 acc[4][4];
    for (int mi = 0; mi < 4; ++mi) for (int ni = 0; ni < 4; ++ni)
        for (int r = 0; r < 4; ++r) acc[mi][ni][r] = 0.f;

    for (int kt = 0; kt < DIM / BK; ++kt) {
        #pragma unroll
        for (int j = 0; j < 2; ++j) {
            const int c = w * 2 + j;                    // chunk 0..7 (16 rows each)
            GL_LDS16(&xb[(row0 + c * 16 + lr) * DIM + kt * BK + lco], &As[c * 512]);
            GL_LDS16(&W [(col0 + c * 16 + lr) * DIM + kt * BK + lco], &Bs[c * 512]);
        }
        __syncthreads();   // drains vmcnt(0) -> staging visible
        bf16x8 af[4], bfr[4];
        #pragma unroll
        for (int mi = 0; mi < 4; ++mi)
            af[mi] = *(const bf16x8*)&As[(wy * 64 + mi * 16 + l15) * BK + quad * 8];
        #pragma unroll
        for (int ni = 0; ni < 4; ++ni)
            bfr[ni] = *(const bf16x8*)&Bs[(wx * 64 + ni * 16 + l15) * BK + quad * 8];
        #pragma unroll
        for (int mi = 0; mi < 4; ++mi)
            #pragma unroll
            for (int ni = 0; ni < 4; ++ni)
                acc[mi][ni] = __builtin_amdgcn_mfma_f32_16x16x32_bf16(af[mi], bfr[ni], acc[mi][ni], 0, 0, 0);
        __syncthreads();   // all reads done before next overwrite
    }

    // qscale folds 1/sqrt(48) and log2(e) (softmax uses exp2)
    const float qscale = 0.14433756729740643f * 1.4426950408889634f;

    if (z == 2) {
        // V^T epilogue: r-loop is contiguous in s -> pack 4 bf16 = one 8B store
        #pragma unroll
        for (int mi = 0; mi < 4; ++mi) {
            #pragma unroll
            for (int ni = 0; ni < 4; ++ni) {
                int col = col0 + wx * 64 + ni * 16 + l15;
                int h = col / DH, d = col - h * DH;
                int row = row0 + wy * 64 + mi * 16 + quad * 4;   // r=0 token
                int b = row >> 11, s = row & 2047;
                float bi = bias[col];
                union { ushort4 v; unsigned short e[4]; } pk;
                #pragma unroll
                for (int r = 0; r < 4; ++r)
                    pk.e[r] = f32_to_bf16(acc[mi][ni][r] + bi);
                *(ushort4*)&Vt[((b * NH + h) * DP + d) * SEQ + s] = pk.v;
            }
        }
    } else {
        #pragma unroll
        for (int mi = 0; mi < 4; ++mi) {
            #pragma unroll
            for (int ni = 0; ni < 4; ++ni) {
                #pragma unroll
                for (int r = 0; r < 4; ++r) {
                    int row = row0 + wy * 64 + mi * 16 + quad * 4 + r;
                    int col = col0 + wx * 64 + ni * 16 + l15;
                    float v = acc[mi][ni][r] + bias[col];
                    int b = row >> 11, s = row & 2047;
                    int h = col / DH, d = col - h * DH;
                    int bh = b * NH + h;
                    if (z == 0) Qb[(bh * SEQ + s) * DP + d] = f32_to_bf16(v * qscale);
                    else        Kb[(bh * SEQ + s) * DP + d] = f32_to_bf16(v);
                }
            }
        }
    }
}

__global__ __launch_bounds__(256) void out_gemm(
    const unsigned short* __restrict__ ab,
    const unsigned short* __restrict__ Wo,
    const float* __restrict__ bo,
    float* __restrict__ out)
{
    const int row0 = blockIdx.x * 128;
    const int col0 = blockIdx.y * 128;

    __shared__ __align__(16) short As[128 * BK];
    __shared__ __align__(16) short Bs[128 * BK];

    const int tid = threadIdx.x;
    const int lane = tid & 63;
    const int w = tid >> 6;
    const int wy = w >> 1, wx = w & 1;
    const int l15 = lane & 15, quad = lane >> 4;
    const int lr = lane >> 2;
    const int lco = (lane & 3) * 8;

    f32x4 acc[4][4];
    for (int mi = 0; mi < 4; ++mi) for (int ni = 0; ni < 4; ++ni)
        for (int r = 0; r < 4; ++r) acc[mi][ni][r] = 0.f;

    for (int kt = 0; kt < DIM / BK; ++kt) {
        #pragma unroll
        for (int j = 0; j < 2; ++j) {
            const int c = w * 2 + j;                    // chunk 0..7
            GL_LDS16(&ab[(row0 + c * 16 + lr) * DIM + kt * BK + lco], &As[c * 512]);
            GL_LDS16(&Wo[(col0 + c * 16 + lr) * DIM + kt * BK + lco], &Bs[c * 512]);
        }
        __syncthreads();
        bf16x8 af[4], bfr[4];
        #pragma unroll
        for (int mi = 0; mi < 4; ++mi)
            af[mi] = *(const bf16x8*)&As[(wy * 64 + mi * 16 + l15) * BK + quad * 8];
        #pragma unroll
        for (int ni = 0; ni < 4; ++ni)
            bfr[ni] = *(const bf16x8*)&Bs[(wx * 64 + ni * 16 + l15) * BK + quad * 8];
        #pragma unroll
        for (int mi = 0; mi < 4; ++mi)
            #pragma unroll
            for (int ni = 0; ni < 4; ++ni)
                acc[mi][ni] = __builtin_amdgcn_mfma_f32_16x16x32_bf16(af[mi], bfr[ni], acc[mi][ni], 0, 0, 0);
        __syncthreads();
    }

    #pragma unroll
    for (int mi = 0; mi < 4; ++mi)
        #pragma unroll
        for (int ni = 0; ni < 4; ++ni)
            #pragma unroll
            for (int r = 0; r < 4; ++r) {
                int row = row0 + wy * 64 + mi * 16 + quad * 4 + r;
                int col = col0 + wx * 64 + ni * 16 + l15;
                out[row * DIM + col] = acc[mi][ni][r] + bo[col];
            }
}

// ---------------- flash attention: 64 q-rows/wave, gl_lds double-buffer ----------------
// r0's compute core verbatim (4 m-sets/wave, VALU lsum chains, av[2][3]).
// ONLY staging changed: global_load_lds into a 2x(8KB K + 6KB V) double buffer,
// swizzle folded into the per-lane GLOBAL source address (r2-proven geometry;
// LDS dest stays wave-uniform base + lane*16 -> write-side conflict-free).
// kt-loop unrolled x2 for compile-time buffer indices; ONE barrier per kt
// (next tile's loads issued first, land during the ~2us compute phase; the
// barrier's vmcnt(0) drain then costs ~nothing). Removes r0's 4 ds_writes +
// 4 reg round-trips per thread/kt, 32 barriers, ~16 prefetch VGPRs, and the
// 1.83M write-side bank conflicts.
__device__ __forceinline__ int keyperm(int a) {
    return (a & 32) + ((a & 12) << 1) + ((a & 16) >> 2) + (a & 3);
}

__global__ __launch_bounds__(256) void attn_kernel(
    const unsigned short* __restrict__ Qb,
    const unsigned short* __restrict__ Kb,
    const unsigned short* __restrict__ Vt,
    unsigned short* __restrict__ Ob)
{
    const int bh = blockIdx.x;
    const int tile = blockIdx.y;
    const int tid = threadIdx.x;
    const int w = tid >> 6;            // 0..3
    const int lane = tid & 63;
    const int l15 = lane & 15, quad = lane >> 4;

    const unsigned short* Qh = Qb + bh * SEQ * DP;
    const unsigned short* Kh = Kb + bh * SEQ * DP;
    const unsigned short* Vh = Vt + bh * DP * SEQ;
    const int q0 = tile * 256 + w * 64;

    // double-buffered; pitch 64 shorts (128B), 16B-chunk XOR swizzle
    // (phys chunk = logical ^ (row&7)), folded into the global source address.
    __shared__ __align__(16) short Ks[2][64 * 64];   // [slot a -> global key keyperm(a)][d]
    __shared__ __align__(16) short Vs[2][48 * 64];   // [d][key], identity key order

    // Q B-operand fragments (loop-invariant); zero the d>=48 pad in registers.
    bf16x8 aq[4][2];
    #pragma unroll
    for (int m = 0; m < 4; ++m)
        #pragma unroll
        for (int ks = 0; ks < 2; ++ks)
            aq[m][ks] = *(const bf16x8*)&Qh[(q0 + m * 16 + l15) * DP + ks * 32 + quad * 8];
    if (quad >= 2) {
        const bf16x8 z8 = {0, 0, 0, 0, 0, 0, 0, 0};
        #pragma unroll
        for (int m = 0; m < 4; ++m) aq[m][1] = z8;
    }

    f32x4 o[4][3];
    #pragma unroll
    for (int m = 0; m < 4; ++m) for (int ni = 0; ni < 3; ++ni)
        for (int r = 0; r < 4; ++r) o[m][ni][r] = 0.f;
    float ls[4][2];
    #pragma unroll
    for (int m = 0; m < 4; ++m) { ls[m][0] = 0.f; ls[m][1] = 0.f; }

    const f32x4 FZ = {0.f, 0.f, 0.f, 0.f};   // loop-invariant zero C operand

    // ---- staging geometry (global_load_lds, 1024B chunks; r2-proven) ----
    // chunk c: LDS bytes [c*1024, c*1024+1024), lane writes c*1024 + lane*16
    //   -> row ra = c*8 + (lane>>3), 16B-chunk-in-row pcc = lane&7
    // K tile 8KB = 8 chunks: wave w stages c = 2w, 2w+1.
    // V tile 6KB = 6 chunks: waves 0..2 stage c = 2w, 2w+1 (wave-uniform predicate).
    const int lr3 = lane >> 3, pcc = lane & 7;
    int kso[2], vso[2];                          // per-lane global short offsets
    #pragma unroll
    for (int j = 0; j < 2; ++j) {
        const int c = w * 2 + j;
        const int ra = c * 8 + lr3;
        const int swz8 = ((pcc ^ (ra & 7)) * 8); // swizzled short offset within row
        kso[j] = keyperm(ra) * DP + swz8;        // + k0*DP at issue time
        vso[j] = ra * SEQ + swz8;                // + k0 at issue time (w<3 only)
    }
    const bool vld = (w < 3);

    // prologue: stage kt=0 into buffer 0, then drain
    #pragma unroll
    for (int j = 0; j < 2; ++j) {
        GL_LDS16(&Kh[kso[j]], &Ks[0][(w * 2 + j) * 512]);
        if (vld) GL_LDS16(&Vh[vso[j]], &Vs[0][(w * 2 + j) * 512]);
    }
    __syncthreads();

#define ATTN_STEP(B, KT) do { \
    if ((KT) + 1 < SEQ / 64) { \
        const int k0n = ((KT) + 1) * 64; \
        _Pragma("unroll") \
        for (int j = 0; j < 2; ++j) { \
            GL_LDS16(&Kh[k0n * DP + kso[j]], &Ks[(B) ^ 1][(w * 2 + j) * 512]); \
            if (vld) GL_LDS16(&Vh[k0n + vso[j]], &Vs[(B) ^ 1][(w * 2 + j) * 512]); \
        } \
    } \
    bf16x8 ak0[4], ak1[4]; \
    _Pragma("unroll") \
    for (int n = 0; n < 4; ++n) { \
        ak0[n] = *(const bf16x8*)&Ks[B][(n * 16 + l15) * 64 + ((quad ^ (l15 & 7)) * 8)]; \
        ak1[n] = *(const bf16x8*)&Ks[B][(n * 16 + l15) * 64 + (((4 + quad) ^ (l15 & 7)) * 8)]; \
    } \
    bf16x8 av[2][3]; \
    _Pragma("unroll") \
    for (int ks = 0; ks < 2; ++ks) \
        _Pragma("unroll") \
        for (int mt = 0; mt < 3; ++mt) \
            av[ks][mt] = *(const bf16x8*)&Vs[B][(mt * 16 + l15) * 64 + (((ks * 4 + quad) ^ (l15 & 7)) * 8)]; \
    _Pragma("unroll") \
    for (int mp = 0; mp < 2; ++mp) { \
        const int m0 = 2 * mp, m1 = 2 * mp + 1; \
        f32x4 sc[2][4]; \
        _Pragma("unroll") \
        for (int n = 0; n < 4; ++n) { \
            sc[0][n] = __builtin_amdgcn_mfma_f32_16x16x32_bf16(ak0[n], aq[m0][0], FZ, 0, 0, 0); \
            sc[1][n] = __builtin_amdgcn_mfma_f32_16x16x32_bf16(ak0[n], aq[m1][0], FZ, 0, 0, 0); \
        } \
        _Pragma("unroll") \
        for (int n = 0; n < 4; ++n) { \
            sc[0][n] = __builtin_amdgcn_mfma_f32_16x16x32_bf16(ak1[n], aq[m0][1], sc[0][n], 0, 0, 0); \
            sc[1][n] = __builtin_amdgcn_mfma_f32_16x16x32_bf16(ak1[n], aq[m1][1], sc[1][n], 0, 0, 0); \
        } \
        union { u32x4 u; bf16x8 h; } bp[2][2]; \
        _Pragma("unroll") \
        for (int mi = 0; mi < 2; ++mi) { \
            _Pragma("unroll") \
            for (int ks = 0; ks < 2; ++ks) { \
                _Pragma("unroll") \
                for (int w2 = 0; w2 < 4; ++w2) { \
                    const int j0 = 2 * w2, j1 = 2 * w2 + 1; \
                    float p0 = EXP2F(sc[mi][2 * ks + (j0 >> 2)][j0 & 3]); \
                    float p1 = EXP2F(sc[mi][2 * ks + (j1 >> 2)][j1 & 3]); \
                    ls[2 * mp + mi][w2 & 1] += (p0 + p1); \
                    bp[mi][ks].u[w2] = __builtin_amdgcn_perm(__float_as_uint(p1), __float_as_uint(p0), 0x07060302u); \
                } \
            } \
        } \
        _Pragma("unroll") \
        for (int ks = 0; ks < 2; ++ks) \
            _Pragma("unroll") \
            for (int mt = 0; mt < 3; ++mt) { \
                o[m0][mt] = __builtin_amdgcn_mfma_f32_16x16x32_bf16(av[ks][mt], bp[0][ks].h, o[m0][mt], 0, 0, 0); \
                o[m1][mt] = __builtin_amdgcn_mfma_f32_16x16x32_bf16(av[ks][mt], bp[1][ks].h, o[m1][mt], 0, 0, 0); \
            } \
    } \
    __syncthreads(); \
} while (0)

    for (int kt = 0; kt < SEQ / 64; kt += 2) {
        ATTN_STEP(0, kt);
        ATTN_STEP(1, kt + 1);
    }

    // ---- row-sum: combine 2 chains, then cross-quad; packed ushort4 stores ----
    const int b = bh >> 4, h = bh & 15;
    #pragma unroll
    for (int m = 0; m < 4; ++m) {
        float lsum = ls[m][0] + ls[m][1];
        lsum += __shfl_xor(lsum, 16);
        lsum += __shfl_xor(lsum, 32);
        float inv = 1.f / lsum;
        int token = b * SEQ + q0 + m * 16 + l15;
        #pragma unroll
        for (int mt = 0; mt < 3; ++mt) {
            union { ushort4 v; unsigned short e[4]; } pk;
            #pragma unroll
            for (int r = 0; r < 4; ++r)
                pk.e[r] = f32_to_bf16(o[m][mt][r] * inv);
            *(ushort4*)&Ob[token * DIM + h * DH + mt * 16 + quad * 4] = pk.v;
        }
    }
}

// ---------------- launch ----------------
extern "C" void kernel_launch(void* const* d_in, const int* in_sizes, int n_in,
                              void* d_out, int out_size, void* d_ws, size_t ws_size,
                              hipStream_t stream) {
    const float* x  = (const float*)d_in[0];
    const float* Wq = (const float*)d_in[1]; const float* bq = (const float*)d_in[2];
    const float* Wk = (const float*)d_in[3]; const float* bk = (const float*)d_in[4];
    const float* Wv = (const float*)d_in[5]; const float* bv = (const float*)d_in[6];
    const float* Wo = (const float*)d_in[7]; const float* bo = (const float*)d_in[8];

    unsigned char* ws = (unsigned char*)d_ws;
    unsigned short* xb = (unsigned short*)(ws);                         // 12,582,912 B
    unsigned short* wb = (unsigned short*)(ws + 12582912);              //  4,718,592 B
    unsigned short* Qb = (unsigned short*)(ws + 17301504);              // 16,777,216 B
    unsigned short* Kb = (unsigned short*)(ws + 34078720);              // 16,777,216 B
    unsigned short* Vt = (unsigned short*)(ws + 50855936);              // 16,777,216 B
    unsigned short* Ob = (unsigned short*)(ws + 67633152);              // 12,582,912 B

    cvt_f32_bf16<<<6144, 256, 0, stream>>>(x, xb, MTOK * DIM);
    cvt4_f32_bf16<<<dim3(576, 4), 256, 0, stream>>>(Wq, Wk, Wv, Wo, wb, DIM * DIM);

    qkv_gemm<<<dim3(MTOK / 128, DIM / 128, 3), 256, 0, stream>>>(xb, wb, bq, bk, bv, Qb, Kb, Vt);
    attn_kernel<<<dim3(BHN, SEQ / 256), 256, 0, stream>>>(Qb, Kb, Vt, Ob);
    out_gemm<<<dim3(MTOK / 128, DIM / 128), 256, 0, stream>>>(Ob, wb + 3 * DIM * DIM, bo, (float*)d_out);
}

// Round 6
// 239.021 us; speedup vs baseline: 1.1666x; 1.0370x over previous
//
#include <hip/hip_runtime.h>

#define DIM 768
#define SEQ 2048
#define NB 4
#define NH 16
#define DH 48
#define DP 64      // padded head dim
#define BHN (NB*NH)
#define MTOK (NB*SEQ)   // 8192

typedef __attribute__((ext_vector_type(8))) short bf16x8;
typedef __attribute__((ext_vector_type(4))) float f32x4;
typedef __attribute__((ext_vector_type(4))) unsigned int u32x4;

__device__ __forceinline__ unsigned short f32_to_bf16(float f) {
    union { float f; unsigned int u; } v; v.f = f;
    unsigned int r = v.u + 0x7fff + ((v.u >> 16) & 1);
    return (unsigned short)(r >> 16);
}

#if __has_builtin(__builtin_amdgcn_exp2f)
#define EXP2F(x) __builtin_amdgcn_exp2f(x)
#else
#define EXP2F(x) exp2f(x)
#endif

// async global->LDS, 16B per lane; LDS dest is wave-uniform base + lane*16
#define GL_LDS16(g, l) __builtin_amdgcn_global_load_lds( \
    (const __attribute__((address_space(1))) void*)(g),  \
    (__attribute__((address_space(3))) void*)(l), 16, 0, 0)

// ---------------- fp32 -> bf16 converts ----------------
__global__ void cvt_f32_bf16(const float* __restrict__ src, unsigned short* __restrict__ dst, int n) {
    int i = (blockIdx.x * blockDim.x + threadIdx.x) * 4;
    if (i + 3 < n) {
        const float4 v = *(const float4*)(src + i);
        ushort4 o;
        o.x = f32_to_bf16(v.x); o.y = f32_to_bf16(v.y);
        o.z = f32_to_bf16(v.z); o.w = f32_to_bf16(v.w);
        *(ushort4*)(dst + i) = o;
    }
}

// 4 equal-size weight matrices in one launch (blockIdx.y selects)
__global__ void cvt4_f32_bf16(const float* __restrict__ a, const float* __restrict__ b,
                              const float* __restrict__ c, const float* __restrict__ d,
                              unsigned short* __restrict__ dst, int n_each) {
    const float* srcs[4] = {a, b, c, d};
    const float* src = srcs[blockIdx.y];
    unsigned short* out = dst + blockIdx.y * n_each;
    int i = (blockIdx.x * blockDim.x + threadIdx.x) * 4;
    if (i + 3 < n_each) {
        const float4 v = *(const float4*)(src + i);
        ushort4 o;
        o.x = f32_to_bf16(v.x); o.y = f32_to_bf16(v.y);
        o.z = f32_to_bf16(v.z); o.w = f32_to_bf16(v.w);
        *(ushort4*)(out + i) = o;
    }
}

// ---------------- GEMM: Y = X @ W^T + b ----------------
// 128x128 tile, BK=32, LDS pitch 32, staging via global_load_lds x16B.
// Double-buffered, stage-early, ONE barrier per kt (r3-validated: non-attn
// residual 137.6us vs ~148-150us single-buffered). kt unrolled x2 for static
// LDS buffer indices.
#define BK 32

__global__ __launch_bounds__(256) void qkv_gemm(
    const unsigned short* __restrict__ xb,
    const unsigned short* __restrict__ wb,
    const float* __restrict__ bq, const float* __restrict__ bk, const float* __restrict__ bv,
    unsigned short* __restrict__ Qb, unsigned short* __restrict__ Kb, unsigned short* __restrict__ Vt)
{
    const int z = blockIdx.z;
    const unsigned short* W = wb + z * (DIM * DIM);
    const float* bias = (z == 0) ? bq : (z == 1) ? bk : bv;
    const int row0 = blockIdx.x * 128;
    const int col0 = blockIdx.y * 128;

    __shared__ __align__(16) short As[2][128 * BK];
    __shared__ __align__(16) short Bs[2][128 * BK];

    const int tid = threadIdx.x;
    const int lane = tid & 63;
    const int w = tid >> 6;
    const int wy = w >> 1, wx = w & 1;
    const int l15 = lane & 15, quad = lane >> 4;
    const int lr = lane >> 2;          // row within a 16-row chunk
    const int lco = (lane & 3) * 8;    // short offset within row

    f32x4 acc[4][4];
    for (int mi = 0; mi < 4; ++mi) for (int ni = 0; ni < 4; ++ni)
        for (int r = 0; r < 4; ++r) acc[mi][ni][r] = 0.f;

#define QKV_STAGE(B, KT) do { \
    _Pragma("unroll") \
    for (int j = 0; j < 2; ++j) { \
        const int c = w * 2 + j; \
        GL_LDS16(&xb[(row0 + c * 16 + lr) * DIM + (KT) * BK + lco], &As[B][c * 512]); \
        GL_LDS16(&W [(col0 + c * 16 + lr) * DIM + (KT) * BK + lco], &Bs[B][c * 512]); \
    } } while (0)

#define QKV_COMPUTE(B) do { \
    bf16x8 af[4], bfr[4]; \
    _Pragma("unroll") \
    for (int mi = 0; mi < 4; ++mi) \
        af[mi] = *(const bf16x8*)&As[B][(wy * 64 + mi * 16 + l15) * BK + quad * 8]; \
    _Pragma("unroll") \
    for (int ni = 0; ni < 4; ++ni) \
        bfr[ni] = *(const bf16x8*)&Bs[B][(wx * 64 + ni * 16 + l15) * BK + quad * 8]; \
    _Pragma("unroll") \
    for (int mi = 0; mi < 4; ++mi) \
        _Pragma("unroll") \
        for (int ni = 0; ni < 4; ++ni) \
            acc[mi][ni] = __builtin_amdgcn_mfma_f32_16x16x32_bf16(af[mi], bfr[ni], acc[mi][ni], 0, 0, 0); \
    } while (0)

    QKV_STAGE(0, 0);
    __syncthreads();
    for (int kt = 0; kt < DIM / BK; kt += 2) {
        QKV_STAGE(1, kt + 1);
        QKV_COMPUTE(0);
        __syncthreads();
        if (kt + 2 < DIM / BK) QKV_STAGE(0, kt + 2);
        QKV_COMPUTE(1);
        __syncthreads();
    }

    // qscale folds 1/sqrt(48) and log2(e) (softmax uses exp2)
    const float qscale = 0.14433756729740643f * 1.4426950408889634f;

    if (z == 2) {
        // V^T epilogue: r-loop is contiguous in s -> pack 4 bf16 = one 8B store
        #pragma unroll
        for (int mi = 0; mi < 4; ++mi) {
            #pragma unroll
            for (int ni = 0; ni < 4; ++ni) {
                int col = col0 + wx * 64 + ni * 16 + l15;
                int h = col / DH, d = col - h * DH;
                int row = row0 + wy * 64 + mi * 16 + quad * 4;   // r=0 token
                int b = row >> 11, s = row & 2047;
                float bi = bias[col];
                union { ushort4 v; unsigned short e[4]; } pk;
                #pragma unroll
                for (int r = 0; r < 4; ++r)
                    pk.e[r] = f32_to_bf16(acc[mi][ni][r] + bi);
                *(ushort4*)&Vt[((b * NH + h) * DP + d) * SEQ + s] = pk.v;
            }
        }
    } else {
        #pragma unroll
        for (int mi = 0; mi < 4; ++mi) {
            #pragma unroll
            for (int ni = 0; ni < 4; ++ni) {
                #pragma unroll
                for (int r = 0; r < 4; ++r) {
                    int row = row0 + wy * 64 + mi * 16 + quad * 4 + r;
                    int col = col0 + wx * 64 + ni * 16 + l15;
                    float v = acc[mi][ni][r] + bias[col];
                    int b = row >> 11, s = row & 2047;
                    int h = col / DH, d = col - h * DH;
                    int bh = b * NH + h;
                    if (z == 0) Qb[(bh * SEQ + s) * DP + d] = f32_to_bf16(v * qscale);
                    else        Kb[(bh * SEQ + s) * DP + d] = f32_to_bf16(v);
                }
            }
        }
    }
}

__global__ __launch_bounds__(256) void out_gemm(
    const unsigned short* __restrict__ ab,
    const unsigned short* __restrict__ Wo,
    const float* __restrict__ bo,
    float* __restrict__ out)
{
    const int row0 = blockIdx.x * 128;
    const int col0 = blockIdx.y * 128;

    __shared__ __align__(16) short As[2][128 * BK];
    __shared__ __align__(16) short Bs[2][128 * BK];

    const int tid = threadIdx.x;
    const int lane = tid & 63;
    const int w = tid >> 6;
    const int wy = w >> 1, wx = w & 1;
    const int l15 = lane & 15, quad = lane >> 4;
    const int lr = lane >> 2;
    const int lco = (lane & 3) * 8;

    f32x4 acc[4][4];
    for (int mi = 0; mi < 4; ++mi) for (int ni = 0; ni < 4; ++ni)
        for (int r = 0; r < 4; ++r) acc[mi][ni][r] = 0.f;

#define OUT_STAGE(B, KT) do { \
    _Pragma("unroll") \
    for (int j = 0; j < 2; ++j) { \
        const int c = w * 2 + j; \
        GL_LDS16(&ab[(row0 + c * 16 + lr) * DIM + (KT) * BK + lco], &As[B][c * 512]); \
        GL_LDS16(&Wo[(col0 + c * 16 + lr) * DIM + (KT) * BK + lco], &Bs[B][c * 512]); \
    } } while (0)

    OUT_STAGE(0, 0);
    __syncthreads();
    for (int kt = 0; kt < DIM / BK; kt += 2) {
        OUT_STAGE(1, kt + 1);
        QKV_COMPUTE(0);
        __syncthreads();
        if (kt + 2 < DIM / BK) OUT_STAGE(0, kt + 2);
        QKV_COMPUTE(1);
        __syncthreads();
    }

    #pragma unroll
    for (int mi = 0; mi < 4; ++mi)
        #pragma unroll
        for (int ni = 0; ni < 4; ++ni)
            #pragma unroll
            for (int r = 0; r < 4; ++r) {
                int row = row0 + wy * 64 + mi * 16 + quad * 4 + r;
                int col = col0 + wx * 64 + ni * 16 + l15;
                out[row * DIM + col] = acc[mi][ni][r] + bo[col];
            }
}

// ---------------- flash attention: 64 q-rows/wave (r0 structure) ----------------
// 256 threads = 4 waves, 256 q-rows/block; grid (BHN, SEQ/256) = 512 blocks,
// 2 blocks/CU. r0 compute core verbatim (best measured: 69.8us, VGPR=120).
// ONE graft (r4-verified mapping): staging remap ra=tid>>3, pc=tid&7, each
// thread stages rows ra and ra+32 -> wave ds_writes are lane*16-sequential,
// write-side bank-conflict-free (r0's ra=tid>>2/pc=tid&3 hit half the banks:
// 1.83M conflict cycles). keyperm(ra+32)=keyperm(ra)+32, so the final LDS
// image is IDENTICAL to r0's. V rows 32..47 staged by waves 0-1 (wave-uniform).
__device__ __forceinline__ int keyperm(int a) {
    return (a & 32) + ((a & 12) << 1) + ((a & 16) >> 2) + (a & 3);
}

__global__ __launch_bounds__(256) void attn_kernel(
    const unsigned short* __restrict__ Qb,
    const unsigned short* __restrict__ Kb,
    const unsigned short* __restrict__ Vt,
    unsigned short* __restrict__ Ob)
{
    const int bh = blockIdx.x;
    const int tile = blockIdx.y;
    const int tid = threadIdx.x;
    const int w = tid >> 6;            // 0..3
    const int lane = tid & 63;
    const int l15 = lane & 15, quad = lane >> 4;

    const unsigned short* Qh = Qb + bh * SEQ * DP;
    const unsigned short* Kh = Kb + bh * SEQ * DP;
    const unsigned short* Vh = Vt + bh * DP * SEQ;
    const int q0 = tile * 256 + w * 64;

    // pitch 64, 16B-chunk XOR swizzle (phys chunk = logical ^ (row&7)),
    // absorbed into the global source address at staging time.
    __shared__ __align__(16) short Ks[64 * 64];   // [key slot a -> global key keyperm(a)][d]
    __shared__ __align__(16) short Vs[48 * 64];   // [d][key], identity key order

    // Q B-operand fragments (loop-invariant); zero the d>=48 pad in registers.
    bf16x8 aq[4][2];
    #pragma unroll
    for (int m = 0; m < 4; ++m)
        #pragma unroll
        for (int ks = 0; ks < 2; ++ks)
            aq[m][ks] = *(const bf16x8*)&Qh[(q0 + m * 16 + l15) * DP + ks * 32 + quad * 8];
    if (quad >= 2) {
        const bf16x8 z8 = {0, 0, 0, 0, 0, 0, 0, 0};
        #pragma unroll
        for (int m = 0; m < 4; ++m) aq[m][1] = z8;
    }

    f32x4 o[4][3];
    #pragma unroll
    for (int m = 0; m < 4; ++m) for (int ni = 0; ni < 3; ++ni)
        for (int r = 0; r < 4; ++r) o[m][ni][r] = 0.f;
    float ls[4][2];
    #pragma unroll
    for (int m = 0; m < 4; ++m) { ls[m][0] = 0.f; ls[m][1] = 0.f; }

    const f32x4 FZ = {0.f, 0.f, 0.f, 0.f};   // loop-invariant zero C operand

    // staging: 256 threads; row ra = tid>>3 (0..31) and ra+32; chunk pc = tid&7.
    // Wave lanes write LDS bytes at lane*16-sequential addresses -> conflict-free.
    // Swizzled source chunk = pc ^ (ra&7); identical for ra and ra+32.
    // K: rows ra, ra+32 (all threads). V: rows ra (all) + rows 32..47 (waves 0-1).
    const int ra = tid >> 3;
    const int pc = tid & 7;
    const int lc = (pc ^ (ra & 7)) * 8;          // swizzled short offset within row
    const int kaR = keyperm(ra);
    const int ldsA = ra * 64 + pc * 8;
    const int ldsB = ldsA + 32 * 64;
    const bool v2 = (w < 2);                     // wave-uniform: ra < 16

    bf16x8 kr0, kr1, vr0, vr1;
    kr0 = *(const bf16x8*)&Kh[kaR * DP + lc];
    kr1 = *(const bf16x8*)&Kh[(kaR + 32) * DP + lc];
    vr0 = *(const bf16x8*)&Vh[ra * SEQ + lc];
    if (v2) vr1 = *(const bf16x8*)&Vh[(ra + 32) * SEQ + lc];

    for (int kt = 0; kt < SEQ / 64; ++kt) {
        __syncthreads();
        *(bf16x8*)&Ks[ldsA] = kr0;
        *(bf16x8*)&Ks[ldsB] = kr1;
        *(bf16x8*)&Vs[ldsA] = vr0;
        if (v2) *(bf16x8*)&Vs[ldsB] = vr1;
        if (kt + 1 < SEQ / 64) {
            const int k0n = (kt + 1) * 64;
            kr0 = *(const bf16x8*)&Kh[(k0n + kaR) * DP + lc];
            kr1 = *(const bf16x8*)&Kh[(k0n + kaR + 32) * DP + lc];
            vr0 = *(const bf16x8*)&Vh[ra * SEQ + k0n + lc];
            if (v2) vr1 = *(const bf16x8*)&Vh[(ra + 32) * SEQ + k0n + lc];
        }
        __syncthreads();

        // ---- K/V fragments: read once, serve all 4 m-sets ----
        bf16x8 ak0[4], ak1[4];
        #pragma unroll
        for (int n = 0; n < 4; ++n) {
            ak0[n] = *(const bf16x8*)&Ks[(n * 16 + l15) * 64 + ((quad ^ (l15 & 7)) * 8)];
            ak1[n] = *(const bf16x8*)&Ks[(n * 16 + l15) * 64 + (((4 + quad) ^ (l15 & 7)) * 8)];
        }
        bf16x8 av[2][3];
        #pragma unroll
        for (int ks = 0; ks < 2; ++ks)
            #pragma unroll
            for (int mt = 0; mt < 3; ++mt)
                av[ks][mt] = *(const bf16x8*)&Vs[(mt * 16 + l15) * 64 + (((ks * 4 + quad) ^ (l15 & 7)) * 8)];

        // ---- process 4 m-sets in two pairs (register pressure) ----
        #pragma unroll
        for (int mp = 0; mp < 2; ++mp) {
            const int m0 = 2 * mp, m1 = 2 * mp + 1;
            // S^T = K · Q^T
            f32x4 sc[2][4];
            #pragma unroll
            for (int n = 0; n < 4; ++n) {
                sc[0][n] = __builtin_amdgcn_mfma_f32_16x16x32_bf16(ak0[n], aq[m0][0], FZ, 0, 0, 0);
                sc[1][n] = __builtin_amdgcn_mfma_f32_16x16x32_bf16(ak0[n], aq[m1][0], FZ, 0, 0, 0);
            }
            #pragma unroll
            for (int n = 0; n < 4; ++n) {
                sc[0][n] = __builtin_amdgcn_mfma_f32_16x16x32_bf16(ak1[n], aq[m0][1], sc[0][n], 0, 0, 0);
                sc[1][n] = __builtin_amdgcn_mfma_f32_16x16x32_bf16(ak1[n], aq[m1][1], sc[1][n], 0, 0, 0);
            }
            // P = exp2(S^T); pack 2 vals/instr; 2 lsum chains per m
            union { u32x4 u; bf16x8 h; } bp[2][2];   // [mi][ks]
            #pragma unroll
            for (int mi = 0; mi < 2; ++mi) {
                #pragma unroll
                for (int ks = 0; ks < 2; ++ks) {
                    #pragma unroll
                    for (int w2 = 0; w2 < 4; ++w2) {
                        const int j0 = 2 * w2, j1 = 2 * w2 + 1;
                        float p0 = EXP2F(sc[mi][2 * ks + (j0 >> 2)][j0 & 3]);
                        float p1 = EXP2F(sc[mi][2 * ks + (j1 >> 2)][j1 & 3]);
                        ls[2 * mp + mi][w2 & 1] += (p0 + p1);
                        bp[mi][ks].u[w2] = __builtin_amdgcn_perm(__float_as_uint(p1), __float_as_uint(p0), 0x07060302u);
                    }
                }
            }
            // O += P V
            #pragma unroll
            for (int ks = 0; ks < 2; ++ks)
                #pragma unroll
                for (int mt = 0; mt < 3; ++mt) {
                    o[m0][mt] = __builtin_amdgcn_mfma_f32_16x16x32_bf16(av[ks][mt], bp[0][ks].h, o[m0][mt], 0, 0, 0);
                    o[m1][mt] = __builtin_amdgcn_mfma_f32_16x16x32_bf16(av[ks][mt], bp[1][ks].h, o[m1][mt], 0, 0, 0);
                }
        }
    }

    // ---- row-sum: combine 2 chains, then cross-quad; packed ushort4 stores ----
    const int b = bh >> 4, h = bh & 15;
    #pragma unroll
    for (int m = 0; m < 4; ++m) {
        float lsum = ls[m][0] + ls[m][1];
        lsum += __shfl_xor(lsum, 16);
        lsum += __shfl_xor(lsum, 32);
        float inv = 1.f / lsum;
        int token = b * SEQ + q0 + m * 16 + l15;
        #pragma unroll
        for (int mt = 0; mt < 3; ++mt) {
            union { ushort4 v; unsigned short e[4]; } pk;
            #pragma unroll
            for (int r = 0; r < 4; ++r)
                pk.e[r] = f32_to_bf16(o[m][mt][r] * inv);
            *(ushort4*)&Ob[token * DIM + h * DH + mt * 16 + quad * 4] = pk.v;
        }
    }
}

// ---------------- launch ----------------
extern "C" void kernel_launch(void* const* d_in, const int* in_sizes, int n_in,
                              void* d_out, int out_size, void* d_ws, size_t ws_size,
                              hipStream_t stream) {
    const float* x  = (const float*)d_in[0];
    const float* Wq = (const float*)d_in[1]; const float* bq = (const float*)d_in[2];
    const float* Wk = (const float*)d_in[3]; const float* bk = (const float*)d_in[4];
    const float* Wv = (const float*)d_in[5]; const float* bv = (const float*)d_in[6];
    const float* Wo = (const float*)d_in[7]; const float* bo = (const float*)d_in[8];

    unsigned char* ws = (unsigned char*)d_ws;
    unsigned short* xb = (unsigned short*)(ws);                         // 12,582,912 B
    unsigned short* wb = (unsigned short*)(ws + 12582912);              //  4,718,592 B
    unsigned short* Qb = (unsigned short*)(ws + 17301504);              // 16,777,216 B
    unsigned short* Kb = (unsigned short*)(ws + 34078720);              // 16,777,216 B
    unsigned short* Vt = (unsigned short*)(ws + 50855936);              // 16,777,216 B
    unsigned short* Ob = (unsigned short*)(ws + 67633152);              // 12,582,912 B

    cvt_f32_bf16<<<6144, 256, 0, stream>>>(x, xb, MTOK * DIM);
    cvt4_f32_bf16<<<dim3(576, 4), 256, 0, stream>>>(Wq, Wk, Wv, Wo, wb, DIM * DIM);

    qkv_gemm<<<dim3(MTOK / 128, DIM / 128, 3), 256, 0, stream>>>(xb, wb, bq, bk, bv, Qb, Kb, Vt);
    attn_kernel<<<dim3(BHN, SEQ / 256), 256, 0, stream>>>(Qb, Kb, Vt, Ob);
    out_gemm<<<dim3(MTOK / 128, DIM / 128), 256, 0, stream>>>(Ob, wb + 3 * DIM * DIM, bo, (float*)d_out);
}

// Round 7
// 224.917 us; speedup vs baseline: 1.2397x; 1.0627x over previous
//
#include <hip/hip_runtime.h>

#define DIM 768
#define SEQ 2048
#define NB 4
#define NH 16
#define DH 48
#define DP 64      // padded head dim
#define BHN (NB*NH)
#define MTOK (NB*SEQ)   // 8192

typedef __attribute__((ext_vector_type(8))) short bf16x8;
typedef __attribute__((ext_vector_type(4))) float f32x4;
typedef __attribute__((ext_vector_type(4))) unsigned int u32x4;

__device__ __forceinline__ unsigned short f32_to_bf16(float f) {
    union { float f; unsigned int u; } v; v.f = f;
    unsigned int r = v.u + 0x7fff + ((v.u >> 16) & 1);
    return (unsigned short)(r >> 16);
}

#if __has_builtin(__builtin_amdgcn_exp2f)
#define EXP2F(x) __builtin_amdgcn_exp2f(x)
#else
#define EXP2F(x) exp2f(x)
#endif

// async global->LDS, 16B per lane; LDS dest is wave-uniform base + lane*16
#define GL_LDS16(g, l) __builtin_amdgcn_global_load_lds( \
    (const __attribute__((address_space(1))) void*)(g),  \
    (__attribute__((address_space(3))) void*)(l), 16, 0, 0)

// ---------------- fp32 -> bf16 converts ----------------
__global__ void cvt_f32_bf16(const float* __restrict__ src, unsigned short* __restrict__ dst, int n) {
    int i = (blockIdx.x * blockDim.x + threadIdx.x) * 4;
    if (i + 3 < n) {
        const float4 v = *(const float4*)(src + i);
        ushort4 o;
        o.x = f32_to_bf16(v.x); o.y = f32_to_bf16(v.y);
        o.z = f32_to_bf16(v.z); o.w = f32_to_bf16(v.w);
        *(ushort4*)(dst + i) = o;
    }
}

// 4 equal-size weight matrices in one launch (blockIdx.y selects)
__global__ void cvt4_f32_bf16(const float* __restrict__ a, const float* __restrict__ b,
                              const float* __restrict__ c, const float* __restrict__ d,
                              unsigned short* __restrict__ dst, int n_each) {
    const float* srcs[4] = {a, b, c, d};
    const float* src = srcs[blockIdx.y];
    unsigned short* out = dst + blockIdx.y * n_each;
    int i = (blockIdx.x * blockDim.x + threadIdx.x) * 4;
    if (i + 3 < n_each) {
        const float4 v = *(const float4*)(src + i);
        ushort4 o;
        o.x = f32_to_bf16(v.x); o.y = f32_to_bf16(v.y);
        o.z = f32_to_bf16(v.z); o.w = f32_to_bf16(v.w);
        *(ushort4*)(out + i) = o;
    }
}

// ---------------- GEMM: Y = X @ W^T + b ----------------
// 128x128 tile, BK=64 (12 K-iterations -> half the barrier-drain count of r0's
// BK=32), LDS pitch 64 shorts with the attn-proven 16B-chunk XOR swizzle
// (phys chunk = logical ^ (row&7)) folded into the global staging source.
// Fragment reads are identical in form to attn's ak0/ak1 reads (measured
// 0 bank conflicts). r0's BK=32 pitch-32 reads were 8-way conflicted within
// each 16-lane quarter group (banks {0,16} only at quad=0).
// Tile = 128x64 shorts = 16KB = 16 chunks of 1024B; wave w stages chunks 4w..4w+3.
#define BK 64

__global__ __launch_bounds__(256) void qkv_gemm(
    const unsigned short* __restrict__ xb,
    const unsigned short* __restrict__ wb,
    const float* __restrict__ bq, const float* __restrict__ bk, const float* __restrict__ bv,
    unsigned short* __restrict__ Qb, unsigned short* __restrict__ Kb, unsigned short* __restrict__ Vt)
{
    const int z = blockIdx.z;
    const unsigned short* W = wb + z * (DIM * DIM);
    const float* bias = (z == 0) ? bq : (z == 1) ? bk : bv;
    const int row0 = blockIdx.x * 128;
    const int col0 = blockIdx.y * 128;

    __shared__ __align__(16) short As[128 * BK];
    __shared__ __align__(16) short Bs[128 * BK];

    const int tid = threadIdx.x;
    const int lane = tid & 63;
    const int w = tid >> 6;
    const int wy = w >> 1, wx = w & 1;
    const int l15 = lane & 15, quad = lane >> 4;
    const int lr3 = lane >> 3;         // row within an 8-row chunk
    const int pcc = lane & 7;          // phys 16B-chunk within row

    f32x4 acc[4][4];
    for (int mi = 0; mi < 4; ++mi) for (int ni = 0; ni < 4; ++ni)
        for (int r = 0; r < 4; ++r) acc[mi][ni][r] = 0.f;

    // per-lane staging offsets: chunk c = w*4+j, row ra = c*8+lr3,
    // source col-chunk = pcc ^ (ra&7)  (inverse of the read-side XOR)
    int aro[4];    // row index within tile, per j
    int aco[4];    // swizzled short col offset, per j
    #pragma unroll
    for (int j = 0; j < 4; ++j) {
        const int c = w * 4 + j;
        const int ra = c * 8 + lr3;
        aro[j] = ra;
        aco[j] = (pcc ^ (ra & 7)) * 8;
    }

    for (int kt = 0; kt < DIM / BK; ++kt) {
        #pragma unroll
        for (int j = 0; j < 4; ++j) {
            const int c = w * 4 + j;
            GL_LDS16(&xb[(row0 + aro[j]) * DIM + kt * BK + aco[j]], &As[c * 512]);
            GL_LDS16(&W [(col0 + aro[j]) * DIM + kt * BK + aco[j]], &Bs[c * 512]);
        }
        __syncthreads();   // drains vmcnt(0) -> staging visible
        #pragma unroll
        for (int kk = 0; kk < 2; ++kk) {
            bf16x8 af[4], bfr[4];
            #pragma unroll
            for (int mi = 0; mi < 4; ++mi)
                af[mi] = *(const bf16x8*)&As[(wy * 64 + mi * 16 + l15) * BK + (((kk * 4 + quad) ^ (l15 & 7)) * 8)];
            #pragma unroll
            for (int ni = 0; ni < 4; ++ni)
                bfr[ni] = *(const bf16x8*)&Bs[(wx * 64 + ni * 16 + l15) * BK + (((kk * 4 + quad) ^ (l15 & 7)) * 8)];
            #pragma unroll
            for (int mi = 0; mi < 4; ++mi)
                #pragma unroll
                for (int ni = 0; ni < 4; ++ni)
                    acc[mi][ni] = __builtin_amdgcn_mfma_f32_16x16x32_bf16(af[mi], bfr[ni], acc[mi][ni], 0, 0, 0);
        }
        __syncthreads();   // all reads done before next overwrite
    }

    // qscale folds 1/sqrt(48) and log2(e) (softmax uses exp2)
    const float qscale = 0.14433756729740643f * 1.4426950408889634f;

    if (z == 2) {
        // V^T epilogue: r-loop is contiguous in s -> pack 4 bf16 = one 8B store
        #pragma unroll
        for (int mi = 0; mi < 4; ++mi) {
            #pragma unroll
            for (int ni = 0; ni < 4; ++ni) {
                int col = col0 + wx * 64 + ni * 16 + l15;
                int h = col / DH, d = col - h * DH;
                int row = row0 + wy * 64 + mi * 16 + quad * 4;   // r=0 token
                int b = row >> 11, s = row & 2047;
                float bi = bias[col];
                union { ushort4 v; unsigned short e[4]; } pk;
                #pragma unroll
                for (int r = 0; r < 4; ++r)
                    pk.e[r] = f32_to_bf16(acc[mi][ni][r] + bi);
                *(ushort4*)&Vt[((b * NH + h) * DP + d) * SEQ + s] = pk.v;
            }
        }
    } else {
        #pragma unroll
        for (int mi = 0; mi < 4; ++mi) {
            #pragma unroll
            for (int ni = 0; ni < 4; ++ni) {
                #pragma unroll
                for (int r = 0; r < 4; ++r) {
                    int row = row0 + wy * 64 + mi * 16 + quad * 4 + r;
                    int col = col0 + wx * 64 + ni * 16 + l15;
                    float v = acc[mi][ni][r] + bias[col];
                    int b = row >> 11, s = row & 2047;
                    int h = col / DH, d = col - h * DH;
                    int bh = b * NH + h;
                    if (z == 0) Qb[(bh * SEQ + s) * DP + d] = f32_to_bf16(v * qscale);
                    else        Kb[(bh * SEQ + s) * DP + d] = f32_to_bf16(v);
                }
            }
        }
    }
}

__global__ __launch_bounds__(256) void out_gemm(
    const unsigned short* __restrict__ ab,
    const unsigned short* __restrict__ Wo,
    const float* __restrict__ bo,
    float* __restrict__ out)
{
    const int row0 = blockIdx.x * 128;
    const int col0 = blockIdx.y * 128;

    __shared__ __align__(16) short As[128 * BK];
    __shared__ __align__(16) short Bs[128 * BK];

    const int tid = threadIdx.x;
    const int lane = tid & 63;
    const int w = tid >> 6;
    const int wy = w >> 1, wx = w & 1;
    const int l15 = lane & 15, quad = lane >> 4;
    const int lr3 = lane >> 3;
    const int pcc = lane & 7;

    f32x4 acc[4][4];
    for (int mi = 0; mi < 4; ++mi) for (int ni = 0; ni < 4; ++ni)
        for (int r = 0; r < 4; ++r) acc[mi][ni][r] = 0.f;

    int aro[4], aco[4];
    #pragma unroll
    for (int j = 0; j < 4; ++j) {
        const int c = w * 4 + j;
        const int ra = c * 8 + lr3;
        aro[j] = ra;
        aco[j] = (pcc ^ (ra & 7)) * 8;
    }

    for (int kt = 0; kt < DIM / BK; ++kt) {
        #pragma unroll
        for (int j = 0; j < 4; ++j) {
            const int c = w * 4 + j;
            GL_LDS16(&ab[(row0 + aro[j]) * DIM + kt * BK + aco[j]], &As[c * 512]);
            GL_LDS16(&Wo[(col0 + aro[j]) * DIM + kt * BK + aco[j]], &Bs[c * 512]);
        }
        __syncthreads();
        #pragma unroll
        for (int kk = 0; kk < 2; ++kk) {
            bf16x8 af[4], bfr[4];
            #pragma unroll
            for (int mi = 0; mi < 4; ++mi)
                af[mi] = *(const bf16x8*)&As[(wy * 64 + mi * 16 + l15) * BK + (((kk * 4 + quad) ^ (l15 & 7)) * 8)];
            #pragma unroll
            for (int ni = 0; ni < 4; ++ni)
                bfr[ni] = *(const bf16x8*)&Bs[(wx * 64 + ni * 16 + l15) * BK + (((kk * 4 + quad) ^ (l15 & 7)) * 8)];
            #pragma unroll
            for (int mi = 0; mi < 4; ++mi)
                #pragma unroll
                for (int ni = 0; ni < 4; ++ni)
                    acc[mi][ni] = __builtin_amdgcn_mfma_f32_16x16x32_bf16(af[mi], bfr[ni], acc[mi][ni], 0, 0, 0);
        }
        __syncthreads();
    }

    #pragma unroll
    for (int mi = 0; mi < 4; ++mi)
        #pragma unroll
        for (int ni = 0; ni < 4; ++ni)
            #pragma unroll
            for (int r = 0; r < 4; ++r) {
                int row = row0 + wy * 64 + mi * 16 + quad * 4 + r;
                int col = col0 + wx * 64 + ni * 16 + l15;
                out[row * DIM + col] = acc[mi][ni][r] + bo[col];
            }
}

// ---------------- flash attention: 64 q-rows/wave, register-resident P ----------------
// r0 structure BYTE-IDENTICAL (best measured: 69.8us). 256 threads = 4 waves,
// 256 q-rows/block; grid (BHN, SEQ/256) = 512 blocks, 2 blocks/CU.
__device__ __forceinline__ int keyperm(int a) {
    return (a & 32) + ((a & 12) << 1) + ((a & 16) >> 2) + (a & 3);
}

__global__ __launch_bounds__(256, 2) void attn_kernel(
    const unsigned short* __restrict__ Qb,
    const unsigned short* __restrict__ Kb,
    const unsigned short* __restrict__ Vt,
    unsigned short* __restrict__ Ob)
{
    const int bh = blockIdx.x;
    const int tile = blockIdx.y;
    const int tid = threadIdx.x;
    const int w = tid >> 6;            // 0..3
    const int lane = tid & 63;
    const int l15 = lane & 15, quad = lane >> 4;

    const unsigned short* Qh = Qb + bh * SEQ * DP;
    const unsigned short* Kh = Kb + bh * SEQ * DP;
    const unsigned short* Vh = Vt + bh * DP * SEQ;
    const int q0 = tile * 256 + w * 64;

    // pitch 64, 16B-chunk XOR swizzle (phys chunk = logical ^ (row&7)),
    // absorbed into the global source address at staging time.
    __shared__ __align__(16) short Ks[64 * 64];   // [key slot a -> global key keyperm(a)][d]
    __shared__ __align__(16) short Vs[48 * 64];   // [d][key], identity key order

    // Q B-operand fragments (loop-invariant); zero the d>=48 pad in registers.
    bf16x8 aq[4][2];
    #pragma unroll
    for (int m = 0; m < 4; ++m)
        #pragma unroll
        for (int ks = 0; ks < 2; ++ks)
            aq[m][ks] = *(const bf16x8*)&Qh[(q0 + m * 16 + l15) * DP + ks * 32 + quad * 8];
    if (quad >= 2) {
        const bf16x8 z8 = {0, 0, 0, 0, 0, 0, 0, 0};
        #pragma unroll
        for (int m = 0; m < 4; ++m) aq[m][1] = z8;
    }

    f32x4 o[4][3];
    #pragma unroll
    for (int m = 0; m < 4; ++m) for (int ni = 0; ni < 3; ++ni)
        for (int r = 0; r < 4; ++r) o[m][ni][r] = 0.f;
    float ls[4][2];
    #pragma unroll
    for (int m = 0; m < 4; ++m) { ls[m][0] = 0.f; ls[m][1] = 0.f; }

    const f32x4 FZ = {0.f, 0.f, 0.f, 0.f};   // loop-invariant zero C operand

    // staging: 256 threads; row ra = tid>>2 (0..63), phys chunks pc, pc+4.
    // K: all 64 rows; V: rows 0..47 -> threads < 192 (waves 0..2, wave-uniform).
    const int ra = tid >> 2;
    const int pc = tid & 3;
    const int lcA = ((pc ^ (ra & 7)) * 8);        // swizzled logical short offsets
    const int lcB = (((pc + 4) ^ (ra & 7)) * 8);
    const int kaR = keyperm(ra);
    const int ldsA = ra * 64 + pc * 8;
    const int ldsB = ra * 64 + (pc + 4) * 8;
    const bool vld = (tid < 192);

    bf16x8 kr0, kr1, vr0, vr1;
    kr0 = *(const bf16x8*)&Kh[kaR * DP + lcA];
    kr1 = *(const bf16x8*)&Kh[kaR * DP + lcB];
    if (vld) {
        vr0 = *(const bf16x8*)&Vh[ra * SEQ + lcA];
        vr1 = *(const bf16x8*)&Vh[ra * SEQ + lcB];
    }

    for (int kt = 0; kt < SEQ / 64; ++kt) {
        __syncthreads();
        *(bf16x8*)&Ks[ldsA] = kr0;
        *(bf16x8*)&Ks[ldsB] = kr1;
        if (vld) {
            *(bf16x8*)&Vs[ldsA] = vr0;
            *(bf16x8*)&Vs[ldsB] = vr1;
        }
        if (kt + 1 < SEQ / 64) {
            const int k0n = (kt + 1) * 64;
            kr0 = *(const bf16x8*)&Kh[(k0n + kaR) * DP + lcA];
            kr1 = *(const bf16x8*)&Kh[(k0n + kaR) * DP + lcB];
            if (vld) {
                vr0 = *(const bf16x8*)&Vh[ra * SEQ + k0n + lcA];
                vr1 = *(const bf16x8*)&Vh[ra * SEQ + k0n + lcB];
            }
        }
        __syncthreads();

        // ---- K/V fragments: read once, serve all 4 m-sets ----
        bf16x8 ak0[4], ak1[4];
        #pragma unroll
        for (int n = 0; n < 4; ++n) {
            ak0[n] = *(const bf16x8*)&Ks[(n * 16 + l15) * 64 + ((quad ^ (l15 & 7)) * 8)];
            ak1[n] = *(const bf16x8*)&Ks[(n * 16 + l15) * 64 + (((4 + quad) ^ (l15 & 7)) * 8)];
        }
        bf16x8 av[2][3];
        #pragma unroll
        for (int ks = 0; ks < 2; ++ks)
            #pragma unroll
            for (int mt = 0; mt < 3; ++mt)
                av[ks][mt] = *(const bf16x8*)&Vs[(mt * 16 + l15) * 64 + (((ks * 4 + quad) ^ (l15 & 7)) * 8)];

        // ---- process 4 m-sets in two pairs (register pressure) ----
        #pragma unroll
        for (int mp = 0; mp < 2; ++mp) {
            const int m0 = 2 * mp, m1 = 2 * mp + 1;
            // S^T = K · Q^T
            f32x4 sc[2][4];
            #pragma unroll
            for (int n = 0; n < 4; ++n) {
                sc[0][n] = __builtin_amdgcn_mfma_f32_16x16x32_bf16(ak0[n], aq[m0][0], FZ, 0, 0, 0);
                sc[1][n] = __builtin_amdgcn_mfma_f32_16x16x32_bf16(ak0[n], aq[m1][0], FZ, 0, 0, 0);
            }
            #pragma unroll
            for (int n = 0; n < 4; ++n) {
                sc[0][n] = __builtin_amdgcn_mfma_f32_16x16x32_bf16(ak1[n], aq[m0][1], sc[0][n], 0, 0, 0);
                sc[1][n] = __builtin_amdgcn_mfma_f32_16x16x32_bf16(ak1[n], aq[m1][1], sc[1][n], 0, 0, 0);
            }
            // P = exp2(S^T); pack 2 vals/instr; 2 lsum chains per m
            union { u32x4 u; bf16x8 h; } bp[2][2];   // [mi][ks]
            #pragma unroll
            for (int mi = 0; mi < 2; ++mi) {
                #pragma unroll
                for (int ks = 0; ks < 2; ++ks) {
                    #pragma unroll
                    for (int w2 = 0; w2 < 4; ++w2) {
                        const int j0 = 2 * w2, j1 = 2 * w2 + 1;
                        float p0 = EXP2F(sc[mi][2 * ks + (j0 >> 2)][j0 & 3]);
                        float p1 = EXP2F(sc[mi][2 * ks + (j1 >> 2)][j1 & 3]);
                        ls[2 * mp + mi][w2 & 1] += (p0 + p1);
                        bp[mi][ks].u[w2] = __builtin_amdgcn_perm(__float_as_uint(p1), __float_as_uint(p0), 0x07060302u);
                    }
                }
            }
            // O += P V
            #pragma unroll
            for (int ks = 0; ks < 2; ++ks)
                #pragma unroll
                for (int mt = 0; mt < 3; ++mt) {
                    o[m0][mt] = __builtin_amdgcn_mfma_f32_16x16x32_bf16(av[ks][mt], bp[0][ks].h, o[m0][mt], 0, 0, 0);
                    o[m1][mt] = __builtin_amdgcn_mfma_f32_16x16x32_bf16(av[ks][mt], bp[1][ks].h, o[m1][mt], 0, 0, 0);
                }
        }
    }

    // ---- row-sum: combine 2 chains, then cross-quad; store ----
    const int b = bh >> 4, h = bh & 15;
    #pragma unroll
    for (int m = 0; m < 4; ++m) {
        float lsum = ls[m][0] + ls[m][1];
        lsum += __shfl_xor(lsum, 16);
        lsum += __shfl_xor(lsum, 32);
        float inv = 1.f / lsum;
        #pragma unroll
        for (int mt = 0; mt < 3; ++mt)
            #pragma unroll
            for (int r = 0; r < 4; ++r) {
                int token = b * SEQ + q0 + m * 16 + l15;
                int d = mt * 16 + quad * 4 + r;
                Ob[token * DIM + h * DH + d] = f32_to_bf16(o[m][mt][r] * inv);
            }
    }
}

// ---------------- launch ----------------
extern "C" void kernel_launch(void* const* d_in, const int* in_sizes, int n_in,
                              void* d_out, int out_size, void* d_ws, size_t ws_size,
                              hipStream_t stream) {
    const float* x  = (const float*)d_in[0];
    const float* Wq = (const float*)d_in[1]; const float* bq = (const float*)d_in[2];
    const float* Wk = (const float*)d_in[3]; const float* bk = (const float*)d_in[4];
    const float* Wv = (const float*)d_in[5]; const float* bv = (const float*)d_in[6];
    const float* Wo = (const float*)d_in[7]; const float* bo = (const float*)d_in[8];

    unsigned char* ws = (unsigned char*)d_ws;
    unsigned short* xb = (unsigned short*)(ws);                         // 12,582,912 B
    unsigned short* wb = (unsigned short*)(ws + 12582912);              //  4,718,592 B
    unsigned short* Qb = (unsigned short*)(ws + 17301504);              // 16,777,216 B
    unsigned short* Kb = (unsigned short*)(ws + 34078720);              // 16,777,216 B
    unsigned short* Vt = (unsigned short*)(ws + 50855936);              // 16,777,216 B
    unsigned short* Ob = (unsigned short*)(ws + 67633152);              // 12,582,912 B

    cvt_f32_bf16<<<6144, 256, 0, stream>>>(x, xb, MTOK * DIM);
    cvt4_f32_bf16<<<dim3(576, 4), 256, 0, stream>>>(Wq, Wk, Wv, Wo, wb, DIM * DIM);

    qkv_gemm<<<dim3(MTOK / 128, DIM / 128, 3), 256, 0, stream>>>(xb, wb, bq, bk, bv, Qb, Kb, Vt);
    attn_kernel<<<dim3(BHN, SEQ / 256), 256, 0, stream>>>(Qb, Kb, Vt, Ob);
    out_gemm<<<dim3(MTOK / 128, DIM / 128), 256, 0, stream>>>(Ob, wb + 3 * DIM * DIM, bo, (float*)d_out);
}